// Round 7
// baseline (4274.319 us; speedup 1.0000x reference)
//
#include <hip/hip_runtime.h>
#include <math.h>

#define B_    4096
#define L_    16
#define E_    50
#define EP_   64
#define H_    512
#define G4_   2048
#define V_    128
#define VIS_  2048

typedef unsigned short ushortT;
typedef ushortT ushort8 __attribute__((ext_vector_type(8)));
typedef ushortT ushort4v __attribute__((ext_vector_type(4)));
typedef short   short8  __attribute__((ext_vector_type(8)));
typedef float   f32x4   __attribute__((ext_vector_type(4)));

__device__ __forceinline__ ushortT f2bf(float f) {
  union { float f; unsigned u; } v; v.f = f;
  unsigned u = v.u;
  u += 0x7fffu + ((u >> 16) & 1u);
  return (ushortT)(u >> 16);
}
__device__ __forceinline__ float bf2f(ushortT h) {
  union { unsigned u; float f; } v; v.u = ((unsigned)h) << 16;
  return v.f;
}
__device__ __forceinline__ float sigm(float x) { return 1.f / (1.f + __expf(-x)); }
__device__ __forceinline__ float tanh_f(float x) { return 1.f - 2.f / (__expf(2.f * x) + 1.f); }

// ================================================================ mega prep (grid 34584 x 256)
__global__ void prep_all_k(const float* __restrict__ visual, const int* __restrict__ text,
                           const float* __restrict__ emb,
                           const float* __restrict__ W_ih, const float* __restrict__ W_hh,
                           const float* __restrict__ b_ih, const float* __restrict__ b_hh,
                           const float* __restrict__ W_enc, const float* __restrict__ W_out,
                           const float* __restrict__ W_vis,
                           ushortT* __restrict__ xs_enc, ushortT* __restrict__ xs_dec,
                           ushortT* __restrict__ Whhbf, ushortT* __restrict__ Wihbf,
                           float* __restrict__ biasc, float* __restrict__ biasc0,
                           ushortT* __restrict__ Wvisbf, ushortT* __restrict__ Wencbf,
                           ushortT* __restrict__ Woutbf, ushortT* __restrict__ visbf,
                           int* __restrict__ lens) {
  int bid = blockIdx.x, tid = threadIdx.x;
  if (bid < 16384) {                                  // xs staging [t][b][64] bf16
    int idx = bid * 256 + tid;
    int e = idx & 63, r = idx >> 6, b = r % B_, t = r / B_;
    ushortT ve = 0, vd = 0;
    if (e < E_) {
      int ie = text[b * L_ + t];
      int id = (t == 0) ? 0 : text[b * L_ + t - 1];
      ve = f2bf(emb[ie * E_ + e]);
      vd = f2bf(emb[id * E_ + e]);
    }
    xs_enc[idx] = ve; xs_dec[idx] = vd;
  } else if (bid < 20480) {                           // Whh gate-interleaved bf16 (p=4j+q)
    int idx = (bid - 16384) * 256 + tid;
    int k = idx & 511, p = idx >> 9, j = p >> 2, q = p & 3;
    Whhbf[idx] = f2bf(W_hh[(size_t)(q * H_ + j) * H_ + k]);
  } else if (bid < 20992) {                           // Wih gate-interleaved, padded to 64
    int idx = (bid - 20480) * 256 + tid;
    int k = idx & 63, p = idx >> 6, j = p >> 2, q = p & 3;
    Wihbf[idx] = (k < E_) ? f2bf(W_ih[(size_t)(q * H_ + j) * E_ + k]) : (ushortT)0;
  } else if (bid < 25088) {                           // Wvis
    int idx = (bid - 20992) * 256 + tid;
    Wvisbf[idx] = f2bf(W_vis[idx]);
  } else if (bid < 26112) {                           // Wenc
    int idx = (bid - 25088) * 256 + tid;
    Wencbf[idx] = f2bf(W_enc[idx]);
  } else if (bid < 26368) {                           // Wout
    int idx = (bid - 26112) * 256 + tid;
    Woutbf[idx] = f2bf(W_out[idx]);
  } else if (bid < 34560) {                           // visual fp32 -> bf16 (x4) : 8192 blocks
    int i = (bid - 26368) * 256 + tid;
    float4 v = ((const float4*)visual)[i];
    ushort4v o;
    o[0] = f2bf(v.x); o[1] = f2bf(v.y); o[2] = f2bf(v.z); o[3] = f2bf(v.w);
    ((ushort4v*)visbf)[i] = o;
  } else if (bid < 34576) {                           // lengths (16 blocks)
    int b = (bid - 34560) * 256 + tid;
    int c = 0;
    for (int t = 0; t < L_; ++t) c += (text[b * L_ + t] != 0) ? 1 : 0;
    lens[b] = c;
  } else {                                            // combined bias (+0.1*rowsum for t=0)
    int p = (bid - 34576) * 256 + tid;
    int j = p >> 2, q = p & 3, o = q * H_ + j;
    float base = b_ih[o] + b_hh[o];
    float rs = 0.f;
    const float* wr = W_hh + (size_t)o * H_;
    for (int k = 0; k < H_; ++k) rs += wr[k];
    biasc[p] = base;
    biasc0[p] = base + 0.1f * rs;
  }
}

// ================================================================ weights-slice GEMM (round-5, passing)
__global__ __launch_bounds__(256, 2)
void gemm_ws_k(const ushortT* __restrict__ A, int lda,
               const ushortT* __restrict__ B, int ldb,
               float* __restrict__ Cf, ushortT* __restrict__ Cb,
               int ldc, int Mtot) {
  __shared__ ushortT wlds[64 * 512];
  const int tid = threadIdx.x;
  const int n0 = blockIdx.x * 64;
  const int m0 = blockIdx.y * 256;
  const int kbeg = blockIdx.z * 512;
  const int lane = tid & 63, wave = tid >> 6;
  const int am = lane & 15, ak = (lane >> 4) * 8;
  const int wrow = m0 + wave * 64;

#pragma unroll
  for (int i = 0; i < 16; ++i) {
    int idx = i * 256 + tid;
    int ks = idx >> 8;
    int rem = idx & 255;
    int ni = rem >> 6, ln = rem & 63;
    int row = n0 + ni * 16 + (ln & 15);
    int kc = (ln >> 4) * 8;
    *(ushort8*)(&wlds[idx * 8]) = *(const ushort8*)(&B[(size_t)row * ldb + kbeg + ks * 32 + kc]);
  }
  __syncthreads();

  f32x4 acc[4][4];
#pragma unroll
  for (int i = 0; i < 4; ++i)
#pragma unroll
    for (int j = 0; j < 4; ++j)
#pragma unroll
      for (int r = 0; r < 4; ++r) acc[i][j][r] = 0.f;

#pragma unroll 4
  for (int ks = 0; ks < 16; ++ks) {
    short8 a[4];
#pragma unroll
    for (int mi = 0; mi < 4; ++mi)
      a[mi] = *(const short8*)(&A[(size_t)(wrow + mi * 16 + am) * lda + kbeg + ks * 32 + ak]);
#pragma unroll
    for (int ni = 0; ni < 4; ++ni) {
      short8 b = *(const short8*)(&wlds[((ks * 4 + ni) * 64 + lane) * 8]);
#pragma unroll
      for (int mi = 0; mi < 4; ++mi)
        acc[mi][ni] = __builtin_amdgcn_mfma_f32_16x16x32_bf16(a[mi], b, acc[mi][ni], 0, 0, 0);
    }
  }

  if (Cb) {
#pragma unroll
    for (int mi = 0; mi < 4; ++mi)
#pragma unroll
      for (int r = 0; r < 4; ++r) {
        int m = wrow + mi * 16 + (lane >> 4) * 4 + r;
#pragma unroll
        for (int ni = 0; ni < 4; ++ni)
          Cb[(size_t)m * ldc + n0 + ni * 16 + am] = f2bf(acc[mi][ni][r]);
      }
  } else {
    float* Cz = Cf + (size_t)blockIdx.z * Mtot * ldc;
#pragma unroll
    for (int mi = 0; mi < 4; ++mi)
#pragma unroll
      for (int r = 0; r < 4; ++r) {
        int m = wrow + mi * 16 + (lane >> 4) * 4 + r;
#pragma unroll
        for (int ni = 0; ni < 4; ++ni)
          Cz[(size_t)m * ldc + n0 + ni * 16 + am] = acc[mi][ni][r];
      }
  }
}

// ================================================================ reduce partials + bias/relu + rownorm
__global__ void reduce_norm_k(const float* __restrict__ parts, int nparts,
                              const float* __restrict__ bias, int relu,
                              ushortT* __restrict__ outb, float* __restrict__ outc) {
  int b = blockIdx.x, tid = threadIdx.x;
  float v[2];
  float ss = 0.f;
#pragma unroll
  for (int l = 0; l < 2; ++l) {
    int i = tid + l * 256;
    float s = 0.f;
    for (int p = 0; p < nparts; ++p)
      s += parts[(size_t)p * B_ * H_ + (size_t)b * H_ + i];
    if (bias) s += bias[i];
    if (relu) s = fmaxf(s, 0.f);
    v[l] = s;
    ss += s * s;
  }
  __shared__ float red[256];
  red[tid] = ss; __syncthreads();
  for (int st = 128; st > 0; st >>= 1) { if (tid < st) red[tid] += red[tid + st]; __syncthreads(); }
  float inv = 1.f / sqrtf(red[0]);
#pragma unroll
  for (int l = 0; l < 2; ++l) {
    int i = tid + l * 256;
    float x = v[l] * inv;
    outb[(size_t)b * H_ + i] = f2bf(x);
    if (outc) outc[(size_t)b * H_ + i] = x;
  }
}

// ================================================================ whole-chain encoder LSTM
// 128 blocks x 512 threads; block owns 32 batch rows; h in LDS (dbuf), c in regs.
// Wave w: gate cols [w*256, w*256+256). Weights streamed from L2 (gate-interleaved).
__global__ __launch_bounds__(512, 2)
void enc_chain_k(const ushortT* __restrict__ xs_all, const ushortT* __restrict__ Whh,
                 const ushortT* __restrict__ Wih, const float* __restrict__ biasc,
                 const float* __restrict__ biasc0, ushortT* __restrict__ sel,
                 const int* __restrict__ lens) {
  __shared__ ushortT hl[2][64 * 32 * 8];   // [buf][kblock*32+row][8], 32 KB each
  const int tid = threadIdx.x;
  const int base = blockIdx.x * 32;
  const int lane = tid & 63, wave = tid >> 6;
  const int q = lane >> 4, r = lane & 15;
  const int colbase = wave * 256;
  const int jbase = wave * 64;

  int effm1[2];
#pragma unroll
  for (int mi = 0; mi < 2; ++mi) {
    int row = base + mi * 16 + q * 4 + (r & 3);
    int len = lens[row];
    effm1[mi] = ((len == 0) ? L_ : len) - 1;
  }
  float creg[2][16];
#pragma unroll
  for (int mi = 0; mi < 2; ++mi)
#pragma unroll
    for (int nf = 0; nf < 16; ++nf) creg[mi][nf] = 0.1f;

#pragma unroll 1
  for (int t = 0; t < L_; ++t) {
    f32x4 acc[2][16];
#pragma unroll
    for (int mi = 0; mi < 2; ++mi)
#pragma unroll
      for (int nf = 0; nf < 16; ++nf)
#pragma unroll
        for (int x = 0; x < 4; ++x) acc[mi][nf][x] = 0.f;

    if (t > 0) {
      const ushortT* hb = hl[t & 1];
#pragma unroll 2
      for (int ks = 0; ks < 16; ++ks) {
        short8 a0 = *(const short8*)(&hb[((ks * 4 + q) * 32 + r) * 8]);
        short8 a1 = *(const short8*)(&hb[((ks * 4 + q) * 32 + 16 + r) * 8]);
#pragma unroll
        for (int nf = 0; nf < 16; ++nf) {
          short8 b = *(const short8*)(&Whh[(size_t)(colbase + nf * 16 + r) * H_ + ks * 32 + q * 8]);
          acc[0][nf] = __builtin_amdgcn_mfma_f32_16x16x32_bf16(a0, b, acc[0][nf], 0, 0, 0);
          acc[1][nf] = __builtin_amdgcn_mfma_f32_16x16x32_bf16(a1, b, acc[1][nf], 0, 0, 0);
        }
      }
    }
    const ushortT* xs = xs_all + (size_t)t * B_ * EP_;
#pragma unroll
    for (int xk = 0; xk < 2; ++xk) {
      short8 a0 = *(const short8*)(&xs[(size_t)(base + r) * EP_ + xk * 32 + q * 8]);
      short8 a1 = *(const short8*)(&xs[(size_t)(base + 16 + r) * EP_ + xk * 32 + q * 8]);
#pragma unroll
      for (int nf = 0; nf < 16; ++nf) {
        short8 b = *(const short8*)(&Wih[(size_t)(colbase + nf * 16 + r) * EP_ + xk * 32 + q * 8]);
        acc[0][nf] = __builtin_amdgcn_mfma_f32_16x16x32_bf16(a0, b, acc[0][nf], 0, 0, 0);
        acc[1][nf] = __builtin_amdgcn_mfma_f32_16x16x32_bf16(a1, b, acc[1][nf], 0, 0, 0);
      }
    }

    const float* bc = (t == 0) ? biasc0 : biasc;
    ushortT* hw = hl[(t & 1) ^ 1];
#pragma unroll
    for (int mi = 0; mi < 2; ++mi) {
      int rowl = mi * 16 + q * 4 + (r & 3);
#pragma unroll
      for (int nf = 0; nf < 16; ++nf) {
        float v0 = acc[mi][nf][0], v1 = acc[mi][nf][1], v2 = acc[mi][nf][2], v3 = acc[mi][nf][3];
        float s0 = __shfl_xor(v0, 2), s1 = __shfl_xor(v1, 2),
              s2 = __shfl_xor(v2, 2), s3 = __shfl_xor(v3, 2);
        float a0, a1, a2, a3;
        if (r & 2) { a0 = s2; a1 = s3; a2 = v2; a3 = v3; }
        else       { a0 = v0; a1 = v1; a2 = s0; a3 = s1; }
        float t0 = __shfl_xor(a0, 1), t1 = __shfl_xor(a1, 1),
              t2 = __shfl_xor(a2, 1), t3 = __shfl_xor(a3, 1);
        float g0, g1, g2, g3;
        if (r & 1) { g0 = t1; g1 = a1; g2 = t3; g3 = a3; }
        else       { g0 = a0; g1 = t0; g2 = a2; g3 = t2; }
        int j = jbase + nf * 4 + (r >> 2);
        f32x4 bb = *(const f32x4*)(&bc[j * 4]);
        float si = sigm(g0 + bb[0]);
        float sf = sigm(g1 + bb[1]);
        float tg = tanh_f(g2 + bb[2]);
        float so = sigm(g3 + bb[3]);
        float cn = sf * creg[mi][nf] + si * tg;
        float hn = so * tanh_f(cn);
        creg[mi][nf] = cn;
        ushortT hb16 = f2bf(hn);
        hw[((j >> 3) * 32 + rowl) * 8 + (j & 7)] = hb16;
        if (t == effm1[mi]) sel[(size_t)(base + rowl) * H_ + j] = hb16;
      }
    }
    __syncthreads();
  }
}

// ================================================================ whole-chain decoder LSTM + fused NLL
__global__ __launch_bounds__(512, 2)
void dec_chain_k(const ushortT* __restrict__ xs_all, const ushortT* __restrict__ Whh,
                 const ushortT* __restrict__ Wih, const float* __restrict__ biasc,
                 const float* __restrict__ cinit, const ushortT* __restrict__ h0,
                 const ushortT* __restrict__ Wout, const int* __restrict__ text,
                 float* __restrict__ out) {
  __shared__ ushortT hl[2][64 * 32 * 8];
  const int tid = threadIdx.x;
  const int base = blockIdx.x * 32;
  const int lane = tid & 63, wave = tid >> 6;
  const int q = lane >> 4, r = lane & 15;
  const int colbase = wave * 256;
  const int jbase = wave * 64;

  // preload h0 into buf 0 (k-blocked layout)
#pragma unroll
  for (int i = 0; i < 4; ++i) {
    int idx8 = tid + i * 512;                // 0..2047
    int row = idx8 >> 6, kb = idx8 & 63;
    *(ushort8*)(&hl[0][(kb * 32 + row) * 8]) =
        *(const ushort8*)(&h0[(size_t)(base + row) * H_ + kb * 8]);
  }
  float creg[2][16];
#pragma unroll
  for (int mi = 0; mi < 2; ++mi) {
    int rowl = mi * 16 + q * 4 + (r & 3);
#pragma unroll
    for (int nf = 0; nf < 16; ++nf) {
      int j = jbase + nf * 4 + (r >> 2);
      creg[mi][nf] = cinit[(size_t)(base + rowl) * H_ + j];
    }
  }
  float lossacc[4] = {0.f, 0.f, 0.f, 0.f};
  __syncthreads();

#pragma unroll 1
  for (int t = 0; t < L_; ++t) {
    f32x4 acc[2][16];
#pragma unroll
    for (int mi = 0; mi < 2; ++mi)
#pragma unroll
      for (int nf = 0; nf < 16; ++nf)
#pragma unroll
        for (int x = 0; x < 4; ++x) acc[mi][nf][x] = 0.f;

    const ushortT* hb = hl[t & 1];
#pragma unroll 2
    for (int ks = 0; ks < 16; ++ks) {
      short8 a0 = *(const short8*)(&hb[((ks * 4 + q) * 32 + r) * 8]);
      short8 a1 = *(const short8*)(&hb[((ks * 4 + q) * 32 + 16 + r) * 8]);
#pragma unroll
      for (int nf = 0; nf < 16; ++nf) {
        short8 b = *(const short8*)(&Whh[(size_t)(colbase + nf * 16 + r) * H_ + ks * 32 + q * 8]);
        acc[0][nf] = __builtin_amdgcn_mfma_f32_16x16x32_bf16(a0, b, acc[0][nf], 0, 0, 0);
        acc[1][nf] = __builtin_amdgcn_mfma_f32_16x16x32_bf16(a1, b, acc[1][nf], 0, 0, 0);
      }
    }
    const ushortT* xs = xs_all + (size_t)t * B_ * EP_;
#pragma unroll
    for (int xk = 0; xk < 2; ++xk) {
      short8 a0 = *(const short8*)(&xs[(size_t)(base + r) * EP_ + xk * 32 + q * 8]);
      short8 a1 = *(const short8*)(&xs[(size_t)(base + 16 + r) * EP_ + xk * 32 + q * 8]);
#pragma unroll
      for (int nf = 0; nf < 16; ++nf) {
        short8 b = *(const short8*)(&Wih[(size_t)(colbase + nf * 16 + r) * EP_ + xk * 32 + q * 8]);
        acc[0][nf] = __builtin_amdgcn_mfma_f32_16x16x32_bf16(a0, b, acc[0][nf], 0, 0, 0);
        acc[1][nf] = __builtin_amdgcn_mfma_f32_16x16x32_bf16(a1, b, acc[1][nf], 0, 0, 0);
      }
    }

    ushortT* hw = hl[(t & 1) ^ 1];
#pragma unroll
    for (int mi = 0; mi < 2; ++mi) {
      int rowl = mi * 16 + q * 4 + (r & 3);
#pragma unroll
      for (int nf = 0; nf < 16; ++nf) {
        float v0 = acc[mi][nf][0], v1 = acc[mi][nf][1], v2 = acc[mi][nf][2], v3 = acc[mi][nf][3];
        float s0 = __shfl_xor(v0, 2), s1 = __shfl_xor(v1, 2),
              s2 = __shfl_xor(v2, 2), s3 = __shfl_xor(v3, 2);
        float a0, a1, a2, a3;
        if (r & 2) { a0 = s2; a1 = s3; a2 = v2; a3 = v3; }
        else       { a0 = v0; a1 = v1; a2 = s0; a3 = s1; }
        float t0 = __shfl_xor(a0, 1), t1 = __shfl_xor(a1, 1),
              t2 = __shfl_xor(a2, 1), t3 = __shfl_xor(a3, 1);
        float g0, g1, g2, g3;
        if (r & 1) { g0 = t1; g1 = a1; g2 = t3; g3 = a3; }
        else       { g0 = a0; g1 = t0; g2 = a2; g3 = t2; }
        int j = jbase + nf * 4 + (r >> 2);
        f32x4 bb = *(const f32x4*)(&biasc[j * 4]);
        float si = sigm(g0 + bb[0]);
        float sf = sigm(g1 + bb[1]);
        float tg = tanh_f(g2 + bb[2]);
        float so = sigm(g3 + bb[3]);
        float cn = sf * creg[mi][nf] + si * tg;
        float hn = so * tanh_f(cn);
        creg[mi][nf] = cn;
        hw[((j >> 3) * 32 + rowl) * 8 + (j & 7)] = f2bf(hn);
      }
    }
    __syncthreads();

    // fused NLL for step t: waves 0-1, rows wave*16 + 0..15, from LDS h
    if (wave < 2) {
      f32x4 dacc[8];
#pragma unroll
      for (int nf = 0; nf < 8; ++nf)
#pragma unroll
        for (int x = 0; x < 4; ++x) dacc[nf][x] = 0.f;
#pragma unroll 4
      for (int ks = 0; ks < 16; ++ks) {
        short8 a = *(const short8*)(&hw[((ks * 4 + q) * 32 + wave * 16 + r) * 8]);
#pragma unroll
        for (int nf = 0; nf < 8; ++nf) {
          short8 b = *(const short8*)(&Wout[(size_t)(nf * 16 + r) * H_ + ks * 32 + q * 8]);
          dacc[nf] = __builtin_amdgcn_mfma_f32_16x16x32_bf16(a, b, dacc[nf], 0, 0, 0);
        }
      }
#pragma unroll
      for (int rr = 0; rr < 4; ++rr) {
        float mx = dacc[0][rr];
#pragma unroll
        for (int nf = 1; nf < 8; ++nf) mx = fmaxf(mx, dacc[nf][rr]);
#pragma unroll
        for (int d = 1; d < 16; d <<= 1) mx = fmaxf(mx, __shfl_xor(mx, d));
        float s = 0.f;
#pragma unroll
        for (int nf = 0; nf < 8; ++nf) s += __expf(dacc[nf][rr] - mx);
#pragma unroll
        for (int d = 1; d < 16; d <<= 1) s += __shfl_xor(s, d);
        float lse = mx + __logf(s);
        int row = base + wave * 16 + q * 4 + rr;
        int tgt = text[row * L_ + t];
#pragma unroll
        for (int nf = 0; nf < 8; ++nf)
          if (nf * 16 + r == tgt) lossacc[rr] += lse - dacc[nf][rr];
      }
    }
  }

  if (wave < 2) {
#pragma unroll
    for (int rr = 0; rr < 4; ++rr) {
      float v = lossacc[rr];
#pragma unroll
      for (int d = 1; d < 16; d <<= 1) v += __shfl_xor(v, d);
      if (r == 0) out[base + wave * 16 + q * 4 + rr] = v * (1.f / (float)L_);
    }
  }
}

// ================================================================ softmax / transpose
__global__ __launch_bounds__(256)
void softmax_bf_rows_k(ushortT* __restrict__ P) {
  int rr = blockIdx.x, tid = threadIdx.x;
  ushortT* row = P + (size_t)rr * B_;
  float xv[16];
  float m = -1e30f;
#pragma unroll
  for (int l = 0; l < 16; ++l) { float v = bf2f(row[tid + l * 256]); xv[l] = v; m = fmaxf(m, v); }
  __shared__ float red[256];
  red[tid] = m; __syncthreads();
  for (int st = 128; st > 0; st >>= 1) { if (tid < st) red[tid] = fmaxf(red[tid], red[tid + st]); __syncthreads(); }
  m = red[0]; __syncthreads();
  float s = 0.f;
#pragma unroll
  for (int l = 0; l < 16; ++l) { float e = __expf(xv[l] - m); xv[l] = e; s += e; }
  red[tid] = s; __syncthreads();
  for (int st = 128; st > 0; st >>= 1) { if (tid < st) red[tid] += red[tid + st]; __syncthreads(); }
  float inv = 1.f / red[0];
#pragma unroll
  for (int l = 0; l < 16; ++l) row[tid + l * 256] = f2bf(xv[l] * inv);
}

__global__ void transpose_bf_k(const ushortT* __restrict__ in, ushortT* __restrict__ out,
                               int R, int Ccols) {
  __shared__ ushortT tile[32][33];
  int c0 = blockIdx.x * 32, r0 = blockIdx.y * 32;
  int tx = threadIdx.x & 31, ty = threadIdx.x >> 5;
  for (int i = ty; i < 32; i += 8) tile[i][tx] = in[(size_t)(r0 + i) * Ccols + c0 + tx];
  __syncthreads();
  for (int i = ty; i < 32; i += 8) out[(size_t)(c0 + i) * R + r0 + tx] = tile[tx][i];
}

// ================================================================ launch
extern "C" void kernel_launch(void* const* d_in, const int* in_sizes, int n_in,
                              void* d_out, int out_size, void* d_ws, size_t ws_size,
                              hipStream_t stream) {
  const float* visual = (const float*)d_in[0];
  const int*   text   = (const int*)  d_in[1];
  const float* emb    = (const float*)d_in[2];
  const float* W_ih   = (const float*)d_in[3];
  const float* W_hh   = (const float*)d_in[4];
  const float* b_ih   = (const float*)d_in[5];
  const float* b_hh   = (const float*)d_in[6];
  const float* W_enc  = (const float*)d_in[7];
  const float* b_enc  = (const float*)d_in[8];
  const float* W_out  = (const float*)d_in[9];
  const float* W_vis  = (const float*)d_in[10];
  float* out = (float*)d_out;

  char* w = (char*)d_ws;
  auto alloc = [&](size_t bytes) { char* p = w; w += (bytes + 255) & ~(size_t)255; return p; };
  ushortT* xs_enc  = (ushortT*)alloc((size_t)L_ * B_ * EP_ * 2);
  ushortT* xs_dec  = (ushortT*)alloc((size_t)L_ * B_ * EP_ * 2);
  ushortT* Whhbf   = (ushortT*)alloc((size_t)G4_ * H_ * 2);
  ushortT* Wihbf   = (ushortT*)alloc((size_t)G4_ * EP_ * 2);
  float*   biasc   = (float*)  alloc((size_t)G4_ * 4);
  float*   biasc0  = (float*)  alloc((size_t)G4_ * 4);
  ushortT* Wvisbf  = (ushortT*)alloc((size_t)H_ * VIS_ * 2);
  ushortT* Wencbf  = (ushortT*)alloc((size_t)H_ * H_ * 2);
  ushortT* Woutbf  = (ushortT*)alloc((size_t)V_ * H_ * 2);
  ushortT* visbf   = (ushortT*)alloc((size_t)B_ * VIS_ * 2);
  ushortT* selbf   = (ushortT*)alloc((size_t)B_ * H_ * 2);
  ushortT* vbf     = (ushortT*)alloc((size_t)B_ * H_ * 2);
  ushortT* tencbf  = (ushortT*)alloc((size_t)B_ * H_ * 2);
  ushortT* Pbf     = (ushortT*)alloc((size_t)B_ * B_ * 2);
  ushortT* Vtbf    = (ushortT*)alloc((size_t)H_ * B_ * 2);
  float*   cdec    = (float*)  alloc((size_t)B_ * H_ * 4);
  ushortT* hdec0   = (ushortT*)alloc((size_t)B_ * H_ * 2);
  int*     lens    = (int*)    alloc((size_t)B_ * 4);
  float*   parts   = (float*)  alloc((size_t)8 * B_ * H_ * 4);

  // ---- mega prep (grid must cover all segments; see prep_all_k)
  prep_all_k<<<dim3(34584), dim3(256), 0, stream>>>(
      visual, text, emb, W_ih, W_hh, b_ih, b_hh, W_enc, W_out, W_vis,
      xs_enc, xs_dec, Whhbf, Wihbf, biasc, biasc0,
      Wvisbf, Wencbf, Woutbf, visbf, lens);

  // ---- visual projection (z=4) + rownorm -> vbf
  gemm_ws_k<<<dim3(H_ / 64, B_ / 256, 4), dim3(256), 0, stream>>>(
      visbf, VIS_, Wvisbf, VIS_, parts, nullptr, H_, B_);
  reduce_norm_k<<<dim3(B_), dim3(256), 0, stream>>>(parts, 4, nullptr, 0, vbf, nullptr);

  // ---- encoder LSTM: whole 16-step chain, one launch
  enc_chain_k<<<dim3(B_ / 32), dim3(512), 0, stream>>>(
      xs_enc, Whhbf, Wihbf, biasc, biasc0, selbf, lens);

  // ---- enc linear (z=1) + bias/relu/rownorm -> tencbf
  gemm_ws_k<<<dim3(H_ / 64, B_ / 256, 1), dim3(256), 0, stream>>>(
      selbf, H_, Wencbf, H_, parts, nullptr, H_, B_);
  reduce_norm_k<<<dim3(B_), dim3(256), 0, stream>>>(parts, 1, b_enc, 1, tencbf, nullptr);

  // ---- attention
  gemm_ws_k<<<dim3(B_ / 64, B_ / 256, 1), dim3(256), 0, stream>>>(
      tencbf, H_, vbf, H_, nullptr, Pbf, B_, B_);
  softmax_bf_rows_k<<<dim3(B_), dim3(256), 0, stream>>>(Pbf);
  transpose_bf_k<<<dim3(H_ / 32, B_ / 32), dim3(256), 0, stream>>>(vbf, Vtbf, B_, H_);
  gemm_ws_k<<<dim3(H_ / 64, B_ / 256, 8), dim3(256), 0, stream>>>(
      Pbf, B_, Vtbf, B_, parts, nullptr, H_, B_);
  reduce_norm_k<<<dim3(B_), dim3(256), 0, stream>>>(parts, 8, nullptr, 0, hdec0, cdec);

  // ---- decoder LSTM + fused NLL: whole chain, one launch
  dec_chain_k<<<dim3(B_ / 32), dim3(512), 0, stream>>>(
      xs_dec, Whhbf, Wihbf, biasc, cdec, hdec0, Woutbf, text, out);
}

// Round 8
// 1519.683 us; speedup vs baseline: 2.8126x; 2.8126x over previous
//
#include <hip/hip_runtime.h>
#include <math.h>

#define B_    4096
#define L_    16
#define E_    50
#define EP_   64
#define H_    512
#define G4_   2048
#define V_    128
#define VIS_  2048

typedef unsigned short ushortT;
typedef ushortT ushort8 __attribute__((ext_vector_type(8)));
typedef ushortT ushort4v __attribute__((ext_vector_type(4)));
typedef short   short8  __attribute__((ext_vector_type(8)));
typedef float   f32x4   __attribute__((ext_vector_type(4)));

__device__ __forceinline__ ushortT f2bf(float f) {
  union { float f; unsigned u; } v; v.f = f;
  unsigned u = v.u;
  u += 0x7fffu + ((u >> 16) & 1u);
  return (ushortT)(u >> 16);
}
__device__ __forceinline__ float bf2f(ushortT h) {
  union { unsigned u; float f; } v; v.u = ((unsigned)h) << 16;
  return v.f;
}
__device__ __forceinline__ float sigm(float x) { return 1.f / (1.f + __expf(-x)); }
__device__ __forceinline__ float tanh_f(float x) { return 1.f - 2.f / (__expf(2.f * x) + 1.f); }

// ================================================================ mega prep (grid 30328 x 256)
// seg1 [0,16384): xs staging      seg2 [16384,16960): Wfrag (lstm weights, fragment order)
// seg3 [16960,16992): Woutfrag    seg4 [16992,21088): Wvis cvt
// seg5 [21088,22112): Wenc cvt    seg6 [22112,30304): visual cvt
// seg7 [30304,30320): lengths     seg8 [30320,30328): biasc/biasc0
__global__ void prep_all_k(const float* __restrict__ visual, const int* __restrict__ text,
                           const float* __restrict__ emb,
                           const float* __restrict__ W_ih, const float* __restrict__ W_hh,
                           const float* __restrict__ b_ih, const float* __restrict__ b_hh,
                           const float* __restrict__ W_enc, const float* __restrict__ W_out,
                           const float* __restrict__ W_vis,
                           ushortT* __restrict__ xs_enc, ushortT* __restrict__ xs_dec,
                           ushortT* __restrict__ Wfrag, ushortT* __restrict__ Woutfrag,
                           float* __restrict__ biasc, float* __restrict__ biasc0,
                           ushortT* __restrict__ Wvisbf, ushortT* __restrict__ Wencbf,
                           ushortT* __restrict__ visbf, int* __restrict__ lens) {
  int bid = blockIdx.x, tid = threadIdx.x;
  if (bid < 16384) {                                  // xs staging [t][b][64] bf16
    int idx = bid * 256 + tid;
    int e = idx & 63, r = idx >> 6, b = r % B_, t = r / B_;
    ushortT ve = 0, vd = 0;
    if (e < E_) {
      int ie = text[b * L_ + t];
      int id = (t == 0) ? 0 : text[b * L_ + t - 1];
      ve = f2bf(emb[ie * E_ + e]);
      vd = f2bf(emb[id * E_ + e]);
    }
    xs_enc[idx] = ve; xs_dec[idx] = vd;
  } else if (bid < 16960) {                           // Wfrag: 32 slices x 18 ks x 4 ni x 64 ln (x8)
    int idx8 = (bid - 16384) * 256 + tid;             // 0..147455
    int s = idx8 / 4608;
    int rem = idx8 - s * 4608;
    int ks = rem >> 8;
    int rem2 = rem & 255;
    int ni = rem2 >> 6, ln = rem2 & 63;
    int row = s * 64 + ni * 16 + (ln & 15);           // gate-interleaved row p = 4j+q
    int kc = (ln >> 4) * 8;
    int j = row >> 2, qg = row & 3;
    int srow = qg * H_ + j;
    ushort8 val;
    if (ks < 16) {
      const float* src = W_hh + (size_t)srow * H_ + ks * 32 + kc;
#pragma unroll
      for (int x = 0; x < 8; ++x) val[x] = f2bf(src[x]);
    } else {
      int kb = (ks - 16) * 32 + kc;
#pragma unroll
      for (int x = 0; x < 8; ++x)
        val[x] = (kb + x < E_) ? f2bf(W_ih[(size_t)srow * E_ + kb + x]) : (ushortT)0;
    }
    *(ushort8*)(&Wfrag[(size_t)idx8 * 8]) = val;
  } else if (bid < 16992) {                           // Woutfrag: 16 ks x 8 nf x 64 ln (x8)
    int idx8 = (bid - 16960) * 256 + tid;             // 0..8191
    int ks = idx8 >> 9;
    int rem = idx8 & 511;
    int nf = rem >> 6, ln = rem & 63;
    int row = nf * 16 + (ln & 15);
    int kc = ks * 32 + (ln >> 4) * 8;
    const float* src = W_out + (size_t)row * H_ + kc;
    ushort8 val;
#pragma unroll
    for (int x = 0; x < 8; ++x) val[x] = f2bf(src[x]);
    *(ushort8*)(&Woutfrag[(size_t)idx8 * 8]) = val;
  } else if (bid < 21088) {                           // Wvis
    int idx = (bid - 16992) * 256 + tid;
    Wvisbf[idx] = f2bf(W_vis[idx]);
  } else if (bid < 22112) {                           // Wenc
    int idx = (bid - 21088) * 256 + tid;
    Wencbf[idx] = f2bf(W_enc[idx]);
  } else if (bid < 30304) {                           // visual fp32 -> bf16 (x4)
    int i = (bid - 22112) * 256 + tid;
    float4 v = ((const float4*)visual)[i];
    ushort4v o;
    o[0] = f2bf(v.x); o[1] = f2bf(v.y); o[2] = f2bf(v.z); o[3] = f2bf(v.w);
    ((ushort4v*)visbf)[i] = o;
  } else if (bid < 30320) {                           // lengths
    int b = (bid - 30304) * 256 + tid;
    int c = 0;
    for (int t = 0; t < L_; ++t) c += (text[b * L_ + t] != 0) ? 1 : 0;
    lens[b] = c;
  } else {                                            // biasc / biasc0 (+0.1*rowsum Whh)
    int p = (bid - 30320) * 256 + tid;
    int j = p >> 2, q = p & 3, o = q * H_ + j;
    float base = b_ih[o] + b_hh[o];
    float rs = 0.f;
    const float* wr = W_hh + (size_t)o * H_;
    for (int k = 0; k < H_; ++k) rs += wr[k];
    biasc[p] = base;
    biasc0[p] = base + 0.1f * rs;
  }
}

// ================================================================ weights-slice GEMM (round-5, passing)
__global__ __launch_bounds__(256, 2)
void gemm_ws_k(const ushortT* __restrict__ A, int lda,
               const ushortT* __restrict__ B, int ldb,
               float* __restrict__ Cf, ushortT* __restrict__ Cb,
               int ldc, int Mtot) {
  __shared__ ushortT wlds[64 * 512];
  const int tid = threadIdx.x;
  const int n0 = blockIdx.x * 64;
  const int m0 = blockIdx.y * 256;
  const int kbeg = blockIdx.z * 512;
  const int lane = tid & 63, wave = tid >> 6;
  const int am = lane & 15, ak = (lane >> 4) * 8;
  const int wrow = m0 + wave * 64;

#pragma unroll
  for (int i = 0; i < 16; ++i) {
    int idx = i * 256 + tid;
    int ks = idx >> 8;
    int rem = idx & 255;
    int ni = rem >> 6, ln = rem & 63;
    int row = n0 + ni * 16 + (ln & 15);
    int kc = (ln >> 4) * 8;
    *(ushort8*)(&wlds[idx * 8]) = *(const ushort8*)(&B[(size_t)row * ldb + kbeg + ks * 32 + kc]);
  }
  __syncthreads();

  f32x4 acc[4][4];
#pragma unroll
  for (int i = 0; i < 4; ++i)
#pragma unroll
    for (int j = 0; j < 4; ++j)
#pragma unroll
      for (int r = 0; r < 4; ++r) acc[i][j][r] = 0.f;

#pragma unroll 4
  for (int ks = 0; ks < 16; ++ks) {
    short8 a[4];
#pragma unroll
    for (int mi = 0; mi < 4; ++mi)
      a[mi] = *(const short8*)(&A[(size_t)(wrow + mi * 16 + am) * lda + kbeg + ks * 32 + ak]);
#pragma unroll
    for (int ni = 0; ni < 4; ++ni) {
      short8 b = *(const short8*)(&wlds[((ks * 4 + ni) * 64 + lane) * 8]);
#pragma unroll
      for (int mi = 0; mi < 4; ++mi)
        acc[mi][ni] = __builtin_amdgcn_mfma_f32_16x16x32_bf16(a[mi], b, acc[mi][ni], 0, 0, 0);
    }
  }

  if (Cb) {
#pragma unroll
    for (int mi = 0; mi < 4; ++mi)
#pragma unroll
      for (int r = 0; r < 4; ++r) {
        int m = wrow + mi * 16 + (lane >> 4) * 4 + r;
#pragma unroll
        for (int ni = 0; ni < 4; ++ni)
          Cb[(size_t)m * ldc + n0 + ni * 16 + am] = f2bf(acc[mi][ni][r]);
      }
  } else {
    float* Cz = Cf + (size_t)blockIdx.z * Mtot * ldc;
#pragma unroll
    for (int mi = 0; mi < 4; ++mi)
#pragma unroll
      for (int r = 0; r < 4; ++r) {
        int m = wrow + mi * 16 + (lane >> 4) * 4 + r;
#pragma unroll
        for (int ni = 0; ni < 4; ++ni)
          Cz[(size_t)m * ldc + n0 + ni * 16 + am] = acc[mi][ni][r];
      }
  }
}

// ================================================================ reduce partials + bias/relu + rownorm
__global__ void reduce_norm_k(const float* __restrict__ parts, int nparts,
                              const float* __restrict__ bias, int relu,
                              ushortT* __restrict__ outb, float* __restrict__ outc) {
  int b = blockIdx.x, tid = threadIdx.x;
  float v[2];
  float ss = 0.f;
#pragma unroll
  for (int l = 0; l < 2; ++l) {
    int i = tid + l * 256;
    float s = 0.f;
    for (int p = 0; p < nparts; ++p)
      s += parts[(size_t)p * B_ * H_ + (size_t)b * H_ + i];
    if (bias) s += bias[i];
    if (relu) s = fmaxf(s, 0.f);
    v[l] = s;
    ss += s * s;
  }
  __shared__ float red[256];
  red[tid] = ss; __syncthreads();
  for (int st = 128; st > 0; st >>= 1) { if (tid < st) red[tid] += red[tid + st]; __syncthreads(); }
  float inv = 1.f / sqrtf(red[0]);
#pragma unroll
  for (int l = 0; l < 2; ++l) {
    int i = tid + l * 256;
    float x = v[l] * inv;
    outb[(size_t)b * H_ + i] = f2bf(x);
    if (outc) outc[(size_t)b * H_ + i] = x;
  }
}

// ================================================================ LDS-free fused LSTM step
// grid (32 n-slices, 32 m-tiles); block 256 = 4 waves; wave owns 32 rows x 64 gate-cols.
// Weights pre-swizzled to fragment order (coalesced L2 loads); zero barriers, zero LDS.
__global__ __launch_bounds__(256, 4)
void lstm3_k(const ushortT* __restrict__ hin, const ushortT* __restrict__ Wfrag,
             const ushortT* __restrict__ xs, const float* __restrict__ biasc,
             float* __restrict__ c, int cconst,
             ushortT* __restrict__ hout, ushortT* __restrict__ sel,
             const int* __restrict__ lens, int t) {
  const int tid = threadIdx.x;
  const int slice = blockIdx.x;
  const int m0 = blockIdx.y * 128;
  const int lane = tid & 63, wave = tid >> 6;
  const int q = lane >> 4, r = lane & 15;
  const int ak = q * 8;
  const int wrow = m0 + wave * 32;
  const int jg0 = slice * 16;
  const ushortT* Wf = Wfrag + (size_t)slice * 18 * 4 * 64 * 8;

  f32x4 acc[2][4];
#pragma unroll
  for (int mi = 0; mi < 2; ++mi)
#pragma unroll
    for (int ni = 0; ni < 4; ++ni)
#pragma unroll
      for (int x = 0; x < 4; ++x) acc[mi][ni][x] = 0.f;

#pragma unroll
  for (int xk = 0; xk < 2; ++xk) {
    short8 a0 = *(const short8*)(&xs[(size_t)(wrow + r) * EP_ + xk * 32 + ak]);
    short8 a1 = *(const short8*)(&xs[(size_t)(wrow + 16 + r) * EP_ + xk * 32 + ak]);
#pragma unroll
    for (int ni = 0; ni < 4; ++ni) {
      short8 b = *(const short8*)(&Wf[(((16 + xk) * 4 + ni) * 64 + lane) * 8]);
      acc[0][ni] = __builtin_amdgcn_mfma_f32_16x16x32_bf16(a0, b, acc[0][ni], 0, 0, 0);
      acc[1][ni] = __builtin_amdgcn_mfma_f32_16x16x32_bf16(a1, b, acc[1][ni], 0, 0, 0);
    }
  }
  if (hin) {
#pragma unroll 4
    for (int ks = 0; ks < 16; ++ks) {
      short8 a0 = *(const short8*)(&hin[(size_t)(wrow + r) * H_ + ks * 32 + ak]);
      short8 a1 = *(const short8*)(&hin[(size_t)(wrow + 16 + r) * H_ + ks * 32 + ak]);
#pragma unroll
      for (int ni = 0; ni < 4; ++ni) {
        short8 b = *(const short8*)(&Wf[((ks * 4 + ni) * 64 + lane) * 8]);
        acc[0][ni] = __builtin_amdgcn_mfma_f32_16x16x32_bf16(a0, b, acc[0][ni], 0, 0, 0);
        acc[1][ni] = __builtin_amdgcn_mfma_f32_16x16x32_bf16(a1, b, acc[1][ni], 0, 0, 0);
      }
    }
  }

  // epilogue: shuffle-transpose (verified round 7) + cell update
#pragma unroll
  for (int mi = 0; mi < 2; ++mi) {
    int row = wrow + mi * 16 + q * 4 + (r & 3);
#pragma unroll
    for (int ni = 0; ni < 4; ++ni) {
      float v0 = acc[mi][ni][0], v1 = acc[mi][ni][1], v2 = acc[mi][ni][2], v3 = acc[mi][ni][3];
      float s0 = __shfl_xor(v0, 2), s1 = __shfl_xor(v1, 2),
            s2 = __shfl_xor(v2, 2), s3 = __shfl_xor(v3, 2);
      float a0, a1, a2, a3;
      if (r & 2) { a0 = s2; a1 = s3; a2 = v2; a3 = v3; }
      else       { a0 = v0; a1 = v1; a2 = s0; a3 = s1; }
      float t0 = __shfl_xor(a0, 1), t1 = __shfl_xor(a1, 1),
            t2 = __shfl_xor(a2, 1), t3 = __shfl_xor(a3, 1);
      float g0, g1, g2, g3;
      if (r & 1) { g0 = t1; g1 = a1; g2 = t3; g3 = a3; }
      else       { g0 = a0; g1 = t0; g2 = a2; g3 = t2; }
      int j = jg0 + ni * 4 + (r >> 2);
      f32x4 bb = *(const f32x4*)(&biasc[j * 4]);
      float si = sigm(g0 + bb[0]);
      float sf = sigm(g1 + bb[1]);
      float tg = tanh_f(g2 + bb[2]);
      float so = sigm(g3 + bb[3]);
      size_t ci = (size_t)row * H_ + j;
      float cprev = cconst ? 0.1f : c[ci];
      float cn = sf * cprev + si * tg;
      float hn = so * tanh_f(cn);
      c[ci] = cn;
      ushortT hb16 = f2bf(hn);
      hout[ci] = hb16;
      if (sel) {
        int len = lens[row];
        int eff = (len == 0) ? L_ : len;
        if (t == eff - 1) sel[ci] = hb16;
      }
    }
  }
}

// ================================================================ decoder logits + NLL (coalesced Wout frags)
__global__ __launch_bounds__(256)
void dec_loss3_k(const ushortT* __restrict__ h, const ushortT* __restrict__ Woutfrag,
                 const int* __restrict__ text, int t, float* __restrict__ out) {
  __shared__ float pbuf[4 * 16 * 132];
  const int tid = threadIdx.x;
  const int row0 = blockIdx.x * 16;
  const int lane = tid & 63, wave = tid >> 6;
  const int am = lane & 15, ak = (lane >> 4) * 8;

  f32x4 acc[8];
#pragma unroll
  for (int i = 0; i < 8; ++i)
#pragma unroll
    for (int r = 0; r < 4; ++r) acc[i][r] = 0.f;

#pragma unroll
  for (int ks = 0; ks < 4; ++ks) {
    int ksg = wave * 4 + ks;
    short8 a = *(const short8*)(&h[(size_t)(row0 + am) * H_ + ksg * 32 + ak]);
#pragma unroll
    for (int nf = 0; nf < 8; ++nf) {
      short8 b = *(const short8*)(&Woutfrag[((ksg * 8 + nf) * 64 + lane) * 8]);
      acc[nf] = __builtin_amdgcn_mfma_f32_16x16x32_bf16(a, b, acc[nf], 0, 0, 0);
    }
  }
#pragma unroll
  for (int nf = 0; nf < 8; ++nf)
#pragma unroll
    for (int r = 0; r < 4; ++r) {
      int rowL = (lane >> 4) * 4 + r;
      pbuf[(wave * 16 + rowL) * 132 + nf * 16 + am] = acc[nf][r];
    }
  __syncthreads();

  int row = tid >> 4, lp = tid & 15;
  f32x4 s0, s1;
#pragma unroll
  for (int r = 0; r < 4; ++r) { s0[r] = 0.f; s1[r] = 0.f; }
#pragma unroll
  for (int wv = 0; wv < 4; ++wv) {
    s0 += *(const f32x4*)(&pbuf[(wv * 16 + row) * 132 + lp * 8]);
    s1 += *(const f32x4*)(&pbuf[(wv * 16 + row) * 132 + lp * 8 + 4]);
  }
  float mx = s0[0];
#pragma unroll
  for (int r = 1; r < 4; ++r) mx = fmaxf(mx, s0[r]);
#pragma unroll
  for (int r = 0; r < 4; ++r) mx = fmaxf(mx, s1[r]);
#pragma unroll
  for (int d = 1; d < 16; d <<= 1) mx = fmaxf(mx, __shfl_xor(mx, d));
  float sum = 0.f;
#pragma unroll
  for (int r = 0; r < 4; ++r) sum += __expf(s0[r] - mx) + __expf(s1[r] - mx);
#pragma unroll
  for (int d = 1; d < 16; d <<= 1) sum += __shfl_xor(sum, d);
  float lse = mx + __logf(sum);
  int b = row0 + row;
  int tgt = text[b * L_ + t];
  if ((tgt >> 3) == lp) {
    float lv = (tgt & 4) ? s1[tgt & 3] : s0[tgt & 3];
    float loss = (lse - lv) * (1.f / (float)L_);
    if (t == 0) out[b] = loss;
    else out[b] += loss;
  }
}

// ================================================================ softmax / transpose
__global__ __launch_bounds__(256)
void softmax_bf_rows_k(ushortT* __restrict__ P) {
  int rr = blockIdx.x, tid = threadIdx.x;
  ushortT* row = P + (size_t)rr * B_;
  float xv[16];
  float m = -1e30f;
#pragma unroll
  for (int l = 0; l < 16; ++l) { float v = bf2f(row[tid + l * 256]); xv[l] = v; m = fmaxf(m, v); }
  __shared__ float red[256];
  red[tid] = m; __syncthreads();
  for (int st = 128; st > 0; st >>= 1) { if (tid < st) red[tid] = fmaxf(red[tid], red[tid + st]); __syncthreads(); }
  m = red[0]; __syncthreads();
  float s = 0.f;
#pragma unroll
  for (int l = 0; l < 16; ++l) { float e = __expf(xv[l] - m); xv[l] = e; s += e; }
  red[tid] = s; __syncthreads();
  for (int st = 128; st > 0; st >>= 1) { if (tid < st) red[tid] += red[tid + st]; __syncthreads(); }
  float inv = 1.f / red[0];
#pragma unroll
  for (int l = 0; l < 16; ++l) row[tid + l * 256] = f2bf(xv[l] * inv);
}

__global__ void transpose_bf_k(const ushortT* __restrict__ in, ushortT* __restrict__ out,
                               int R, int Ccols) {
  __shared__ ushortT tile[32][33];
  int c0 = blockIdx.x * 32, r0 = blockIdx.y * 32;
  int tx = threadIdx.x & 31, ty = threadIdx.x >> 5;
  for (int i = ty; i < 32; i += 8) tile[i][tx] = in[(size_t)(r0 + i) * Ccols + c0 + tx];
  __syncthreads();
  for (int i = ty; i < 32; i += 8) out[(size_t)(c0 + i) * R + r0 + tx] = tile[tx][i];
}

// ================================================================ launch
extern "C" void kernel_launch(void* const* d_in, const int* in_sizes, int n_in,
                              void* d_out, int out_size, void* d_ws, size_t ws_size,
                              hipStream_t stream) {
  const float* visual = (const float*)d_in[0];
  const int*   text   = (const int*)  d_in[1];
  const float* emb    = (const float*)d_in[2];
  const float* W_ih   = (const float*)d_in[3];
  const float* W_hh   = (const float*)d_in[4];
  const float* b_ih   = (const float*)d_in[5];
  const float* b_hh   = (const float*)d_in[6];
  const float* W_enc  = (const float*)d_in[7];
  const float* b_enc  = (const float*)d_in[8];
  const float* W_out  = (const float*)d_in[9];
  const float* W_vis  = (const float*)d_in[10];
  float* out = (float*)d_out;

  char* w = (char*)d_ws;
  auto alloc = [&](size_t bytes) { char* p = w; w += (bytes + 255) & ~(size_t)255; return p; };
  ushortT* xs_enc   = (ushortT*)alloc((size_t)L_ * B_ * EP_ * 2);
  ushortT* xs_dec   = (ushortT*)alloc((size_t)L_ * B_ * EP_ * 2);
  ushortT* Wfrag    = (ushortT*)alloc((size_t)32 * 18 * 4 * 64 * 8 * 2);   // 2.25 MB
  ushortT* Woutfrag = (ushortT*)alloc((size_t)16 * 8 * 64 * 8 * 2);        // 128 KB
  float*   biasc    = (float*)  alloc((size_t)G4_ * 4);
  float*   biasc0   = (float*)  alloc((size_t)G4_ * 4);
  ushortT* Wvisbf   = (ushortT*)alloc((size_t)H_ * VIS_ * 2);
  ushortT* Wencbf   = (ushortT*)alloc((size_t)H_ * H_ * 2);
  ushortT* visbf    = (ushortT*)alloc((size_t)B_ * VIS_ * 2);
  ushortT* henc0    = (ushortT*)alloc((size_t)B_ * H_ * 2);
  ushortT* henc1    = (ushortT*)alloc((size_t)B_ * H_ * 2);
  float*   cenc     = (float*)  alloc((size_t)B_ * H_ * 4);
  ushortT* selbf    = (ushortT*)alloc((size_t)B_ * H_ * 2);
  ushortT* vbf      = (ushortT*)alloc((size_t)B_ * H_ * 2);
  ushortT* tencbf   = (ushortT*)alloc((size_t)B_ * H_ * 2);
  ushortT* Pbf      = (ushortT*)alloc((size_t)B_ * B_ * 2);
  ushortT* Vtbf     = (ushortT*)alloc((size_t)H_ * B_ * 2);
  float*   cdec     = (float*)  alloc((size_t)B_ * H_ * 4);
  ushortT* hdec0    = (ushortT*)alloc((size_t)B_ * H_ * 2);
  ushortT* hdec1    = (ushortT*)alloc((size_t)B_ * H_ * 2);
  int*     lens     = (int*)    alloc((size_t)B_ * 4);
  float*   parts    = (float*)  alloc((size_t)8 * B_ * H_ * 4);

  // ---- mega prep
  prep_all_k<<<dim3(30328), dim3(256), 0, stream>>>(
      visual, text, emb, W_ih, W_hh, b_ih, b_hh, W_enc, W_out, W_vis,
      xs_enc, xs_dec, Wfrag, Woutfrag, biasc, biasc0,
      Wvisbf, Wencbf, visbf, lens);

  // ---- visual projection (z=4) + rownorm -> vbf
  gemm_ws_k<<<dim3(H_ / 64, B_ / 256, 4), dim3(256), 0, stream>>>(
      visbf, VIS_, Wvisbf, VIS_, parts, nullptr, H_, B_);
  reduce_norm_k<<<dim3(B_), dim3(256), 0, stream>>>(parts, 4, nullptr, 0, vbf, nullptr);

  // ---- encoder LSTM (per-step, LDS-free; t=0 folds h0 into biasc0)
  for (int t = 0; t < L_; ++t) {
    const ushortT* hin = (t == 0) ? nullptr : ((t & 1) ? henc1 : henc0);
    ushortT* hout = (t & 1) ? henc0 : henc1;
    lstm3_k<<<dim3(32, 32), dim3(256), 0, stream>>>(
        hin, Wfrag, xs_enc + (size_t)t * B_ * EP_,
        (t == 0) ? biasc0 : biasc, cenc, (t == 0) ? 1 : 0,
        hout, selbf, lens, t);
  }

  // ---- enc linear (z=1) + bias/relu/rownorm -> tencbf
  gemm_ws_k<<<dim3(H_ / 64, B_ / 256, 1), dim3(256), 0, stream>>>(
      selbf, H_, Wencbf, H_, parts, nullptr, H_, B_);
  reduce_norm_k<<<dim3(B_), dim3(256), 0, stream>>>(parts, 1, b_enc, 1, tencbf, nullptr);

  // ---- attention
  gemm_ws_k<<<dim3(B_ / 64, B_ / 256, 1), dim3(256), 0, stream>>>(
      tencbf, H_, vbf, H_, nullptr, Pbf, B_, B_);
  softmax_bf_rows_k<<<dim3(B_), dim3(256), 0, stream>>>(Pbf);
  transpose_bf_k<<<dim3(H_ / 32, B_ / 32), dim3(256), 0, stream>>>(vbf, Vtbf, B_, H_);
  gemm_ws_k<<<dim3(H_ / 64, B_ / 256, 8), dim3(256), 0, stream>>>(
      Pbf, B_, Vtbf, B_, parts, nullptr, H_, B_);
  reduce_norm_k<<<dim3(B_), dim3(256), 0, stream>>>(parts, 8, nullptr, 0, hdec0, cdec);

  // ---- decoder LSTM + fused loss (per-step, LDS-free)
  for (int t = 0; t < L_; ++t) {
    const ushortT* hin = (t & 1) ? hdec1 : hdec0;
    ushortT* hout = (t & 1) ? hdec0 : hdec1;
    lstm3_k<<<dim3(32, 32), dim3(256), 0, stream>>>(
        hin, Wfrag, xs_dec + (size_t)t * B_ * EP_,
        biasc, cdec, 0, hout, nullptr, nullptr, t);
    dec_loss3_k<<<dim3(B_ / 16), dim3(256), 0, stream>>>(hout, Woutfrag, text, t, out);
  }
}

// Round 9
// 1370.238 us; speedup vs baseline: 3.1194x; 1.1091x over previous
//
#include <hip/hip_runtime.h>
#include <math.h>

#define B_    4096
#define L_    16
#define E_    50
#define EP_   64
#define H_    512
#define G4_   2048
#define V_    128
#define VIS_  2048

typedef unsigned short ushortT;
typedef ushortT ushort8 __attribute__((ext_vector_type(8)));
typedef ushortT ushort4v __attribute__((ext_vector_type(4)));
typedef short   short8  __attribute__((ext_vector_type(8)));
typedef float   f32x4   __attribute__((ext_vector_type(4)));

__device__ __forceinline__ ushortT f2bf(float f) {
  union { float f; unsigned u; } v; v.f = f;
  unsigned u = v.u;
  u += 0x7fffu + ((u >> 16) & 1u);
  return (ushortT)(u >> 16);
}
__device__ __forceinline__ float bf2f(ushortT h) {
  union { unsigned u; float f; } v; v.u = ((unsigned)h) << 16;
  return v.f;
}
__device__ __forceinline__ float sigm(float x) { return 1.f / (1.f + __expf(-x)); }
__device__ __forceinline__ float tanh_f(float x) { return 1.f - 2.f / (__expf(2.f * x) + 1.f); }

// ================================================================ mega prep (grid 30832 x 256)
// [0,16384) xs | [16384,16960) Wfrag | [16960,16992) Woutfrag | [16992,21088) Wvis
// [21088,22112) Wenc | [22112,30304) visual | [30304,30320) lens | [30320,30832) bias (wave/row)
__global__ void prep_all_k(const float* __restrict__ visual, const int* __restrict__ text,
                           const float* __restrict__ emb,
                           const float* __restrict__ W_ih, const float* __restrict__ W_hh,
                           const float* __restrict__ b_ih, const float* __restrict__ b_hh,
                           const float* __restrict__ W_enc, const float* __restrict__ W_out,
                           const float* __restrict__ W_vis,
                           ushortT* __restrict__ xs_enc, ushortT* __restrict__ xs_dec,
                           ushortT* __restrict__ Wfrag, ushortT* __restrict__ Woutfrag,
                           float* __restrict__ biasc, float* __restrict__ biasc0,
                           ushortT* __restrict__ Wvisbf, ushortT* __restrict__ Wencbf,
                           ushortT* __restrict__ visbf, int* __restrict__ lens) {
  int bid = blockIdx.x, tid = threadIdx.x;
  if (bid < 16384) {                                  // xs staging [t][b][64] bf16
    int idx = bid * 256 + tid;
    int e = idx & 63, r = idx >> 6, b = r % B_, t = r / B_;
    ushortT ve = 0, vd = 0;
    if (e < E_) {
      int ie = text[b * L_ + t];
      int id = (t == 0) ? 0 : text[b * L_ + t - 1];
      ve = f2bf(emb[ie * E_ + e]);
      vd = f2bf(emb[id * E_ + e]);
    }
    xs_enc[idx] = ve; xs_dec[idx] = vd;
  } else if (bid < 16960) {                           // Wfrag: 32 slices x 18 ks x 4 ni x 64 ln (x8)
    int idx8 = (bid - 16384) * 256 + tid;             // 0..147455
    int s = idx8 / 4608;
    int rem = idx8 - s * 4608;
    int ks = rem >> 8;
    int rem2 = rem & 255;
    int ni = rem2 >> 6, ln = rem2 & 63;
    int row = s * 64 + ni * 16 + (ln & 15);           // gate-interleaved row p = 4j+q
    int kc = (ln >> 4) * 8;
    int j = row >> 2, qg = row & 3;
    int srow = qg * H_ + j;
    ushort8 val;
    if (ks < 16) {
      const float* src = W_hh + (size_t)srow * H_ + ks * 32 + kc;
#pragma unroll
      for (int x = 0; x < 8; ++x) val[x] = f2bf(src[x]);
    } else {
      int kb = (ks - 16) * 32 + kc;
#pragma unroll
      for (int x = 0; x < 8; ++x)
        val[x] = (kb + x < E_) ? f2bf(W_ih[(size_t)srow * E_ + kb + x]) : (ushortT)0;
    }
    *(ushort8*)(&Wfrag[(size_t)idx8 * 8]) = val;
  } else if (bid < 16992) {                           // Woutfrag: 16 ks x 8 nf x 64 ln (x8)
    int idx8 = (bid - 16960) * 256 + tid;             // 0..8191
    int ks = idx8 >> 9;
    int rem = idx8 & 511;
    int nf = rem >> 6, ln = rem & 63;
    int row = nf * 16 + (ln & 15);
    int kc = ks * 32 + (ln >> 4) * 8;
    const float* src = W_out + (size_t)row * H_ + kc;
    ushort8 val;
#pragma unroll
    for (int x = 0; x < 8; ++x) val[x] = f2bf(src[x]);
    *(ushort8*)(&Woutfrag[(size_t)idx8 * 8]) = val;
  } else if (bid < 21088) {                           // Wvis
    int idx = (bid - 16992) * 256 + tid;
    Wvisbf[idx] = f2bf(W_vis[idx]);
  } else if (bid < 22112) {                           // Wenc
    int idx = (bid - 21088) * 256 + tid;
    Wencbf[idx] = f2bf(W_enc[idx]);
  } else if (bid < 30304) {                           // visual fp32 -> bf16 (x4)
    int i = (bid - 22112) * 256 + tid;
    float4 v = ((const float4*)visual)[i];
    ushort4v o;
    o[0] = f2bf(v.x); o[1] = f2bf(v.y); o[2] = f2bf(v.z); o[3] = f2bf(v.w);
    ((ushort4v*)visbf)[i] = o;
  } else if (bid < 30320) {                           // lengths
    int b = (bid - 30304) * 256 + tid;
    int c = 0;
    for (int t = 0; t < L_; ++t) c += (text[b * L_ + t] != 0) ? 1 : 0;
    lens[b] = c;
  } else {                                            // biasc / biasc0, one wave per gate-row
    int wave = tid >> 6, lane = tid & 63;
    int p = (bid - 30320) * 4 + wave;                 // 0..2047
    int j = p >> 2, q = p & 3, o = q * H_ + j;
    const float* wr = W_hh + (size_t)o * H_;
    float rs = 0.f;
#pragma unroll
    for (int k = 0; k < H_ / 64; ++k) rs += wr[lane + k * 64];
#pragma unroll
    for (int d = 1; d < 64; d <<= 1) rs += __shfl_xor(rs, d);
    if (lane == 0) {
      float base = b_ih[o] + b_hh[o];
      biasc[p] = base;
      biasc0[p] = base + 0.1f * rs;
    }
  }
}

// ================================================================ weights-slice GEMM (+kchunk)
__global__ __launch_bounds__(256, 2)
void gemm_ws_k(const ushortT* __restrict__ A, int lda,
               const ushortT* __restrict__ B, int ldb, int kchunk,
               float* __restrict__ Cf, ushortT* __restrict__ Cb,
               int ldc, int Mtot) {
  __shared__ ushortT wlds[64 * 512];
  const int tid = threadIdx.x;
  const int n0 = blockIdx.x * 64;
  const int m0 = blockIdx.y * 256;
  const int kbeg0 = blockIdx.z * kchunk;
  const int lane = tid & 63, wave = tid >> 6;
  const int am = lane & 15, ak = (lane >> 4) * 8;
  const int wrow = m0 + wave * 64;

  f32x4 acc[4][4];
#pragma unroll
  for (int i = 0; i < 4; ++i)
#pragma unroll
    for (int j = 0; j < 4; ++j)
#pragma unroll
      for (int r = 0; r < 4; ++r) acc[i][j][r] = 0.f;

  for (int kb = kbeg0; kb < kbeg0 + kchunk; kb += 512) {
#pragma unroll
    for (int i = 0; i < 16; ++i) {
      int idx = i * 256 + tid;
      int ks = idx >> 8;
      int rem = idx & 255;
      int ni = rem >> 6, ln = rem & 63;
      int row = n0 + ni * 16 + (ln & 15);
      int kc = (ln >> 4) * 8;
      *(ushort8*)(&wlds[idx * 8]) = *(const ushort8*)(&B[(size_t)row * ldb + kb + ks * 32 + kc]);
    }
    __syncthreads();
#pragma unroll 4
    for (int ks = 0; ks < 16; ++ks) {
      short8 a[4];
#pragma unroll
      for (int mi = 0; mi < 4; ++mi)
        a[mi] = *(const short8*)(&A[(size_t)(wrow + mi * 16 + am) * lda + kb + ks * 32 + ak]);
#pragma unroll
      for (int ni = 0; ni < 4; ++ni) {
        short8 b = *(const short8*)(&wlds[((ks * 4 + ni) * 64 + lane) * 8]);
#pragma unroll
        for (int mi = 0; mi < 4; ++mi)
          acc[mi][ni] = __builtin_amdgcn_mfma_f32_16x16x32_bf16(a[mi], b, acc[mi][ni], 0, 0, 0);
      }
    }
    __syncthreads();
  }

  if (Cb) {
#pragma unroll
    for (int mi = 0; mi < 4; ++mi)
#pragma unroll
      for (int r = 0; r < 4; ++r) {
        int m = wrow + mi * 16 + (lane >> 4) * 4 + r;
#pragma unroll
        for (int ni = 0; ni < 4; ++ni)
          Cb[(size_t)m * ldc + n0 + ni * 16 + am] = f2bf(acc[mi][ni][r]);
      }
  } else {
    float* Cz = Cf + (size_t)blockIdx.z * Mtot * ldc;
#pragma unroll
    for (int mi = 0; mi < 4; ++mi)
#pragma unroll
      for (int r = 0; r < 4; ++r) {
        int m = wrow + mi * 16 + (lane >> 4) * 4 + r;
#pragma unroll
        for (int ni = 0; ni < 4; ++ni)
          Cz[(size_t)m * ldc + n0 + ni * 16 + am] = acc[mi][ni][r];
      }
  }
}

// ================================================================ reduce partials + bias/relu + rownorm
__global__ void reduce_norm_k(const float* __restrict__ parts, int nparts,
                              const float* __restrict__ bias, int relu,
                              ushortT* __restrict__ outb, float* __restrict__ outc) {
  int b = blockIdx.x, tid = threadIdx.x;
  float v[2];
  float ss = 0.f;
#pragma unroll
  for (int l = 0; l < 2; ++l) {
    int i = tid + l * 256;
    float s = 0.f;
    for (int p = 0; p < nparts; ++p)
      s += parts[(size_t)p * B_ * H_ + (size_t)b * H_ + i];
    if (bias) s += bias[i];
    if (relu) s = fmaxf(s, 0.f);
    v[l] = s;
    ss += s * s;
  }
  __shared__ float red[256];
  red[tid] = ss; __syncthreads();
  for (int st = 128; st > 0; st >>= 1) { if (tid < st) red[tid] += red[tid + st]; __syncthreads(); }
  float inv = 1.f / sqrtf(red[0]);
#pragma unroll
  for (int l = 0; l < 2; ++l) {
    int i = tid + l * 256;
    float x = v[l] * inv;
    outb[(size_t)b * H_ + i] = f2bf(x);
    if (outc) outc[(size_t)b * H_ + i] = x;
  }
}

// ================================================================ LSTM step, 128 gate-cols/block,
// + fused NLL of previous step for grid.x >= 16 (decoder only).
__global__ __launch_bounds__(256, 3)
void lstm4_k(const ushortT* __restrict__ hin, const ushortT* __restrict__ Wfrag,
             const ushortT* __restrict__ xs, const float* __restrict__ biasc,
             float* __restrict__ c, int cconst,
             ushortT* __restrict__ hout, ushortT* __restrict__ sel,
             const int* __restrict__ lens, int t,
             const ushortT* __restrict__ Woutfrag, const int* __restrict__ text,
             float* __restrict__ out, int losst) {
  __shared__ float pbuf[4 * 16 * 132];
  const int tid = threadIdx.x;
  const int lane = tid & 63, wave = tid >> 6;
  const int q = lane >> 4, r = lane & 15;
  const int ak = q * 8;

  if (blockIdx.x >= 16) {
    // ---------------- fused NLL for the PREVIOUS step's h (= hin)
    const int row0 = blockIdx.y * 128 + (blockIdx.x - 16) * 16;
    f32x4 dacc[8];
#pragma unroll
    for (int i = 0; i < 8; ++i)
#pragma unroll
      for (int x = 0; x < 4; ++x) dacc[i][x] = 0.f;
#pragma unroll
    for (int ks = 0; ks < 4; ++ks) {
      int ksg = wave * 4 + ks;
      short8 a = *(const short8*)(&hin[(size_t)(row0 + r) * H_ + ksg * 32 + ak]);
#pragma unroll
      for (int nf = 0; nf < 8; ++nf) {
        short8 b = *(const short8*)(&Woutfrag[((ksg * 8 + nf) * 64 + lane) * 8]);
        dacc[nf] = __builtin_amdgcn_mfma_f32_16x16x32_bf16(a, b, dacc[nf], 0, 0, 0);
      }
    }
#pragma unroll
    for (int nf = 0; nf < 8; ++nf)
#pragma unroll
      for (int rr = 0; rr < 4; ++rr)
        pbuf[(wave * 16 + q * 4 + rr) * 132 + nf * 16 + r] = dacc[nf][rr];
    __syncthreads();
    int row = tid >> 4, lp = tid & 15;
    f32x4 s0, s1;
#pragma unroll
    for (int rr = 0; rr < 4; ++rr) { s0[rr] = 0.f; s1[rr] = 0.f; }
#pragma unroll
    for (int wv = 0; wv < 4; ++wv) {
      s0 += *(const f32x4*)(&pbuf[(wv * 16 + row) * 132 + lp * 8]);
      s1 += *(const f32x4*)(&pbuf[(wv * 16 + row) * 132 + lp * 8 + 4]);
    }
    float mx = s0[0];
#pragma unroll
    for (int rr = 1; rr < 4; ++rr) mx = fmaxf(mx, s0[rr]);
#pragma unroll
    for (int rr = 0; rr < 4; ++rr) mx = fmaxf(mx, s1[rr]);
#pragma unroll
    for (int d = 1; d < 16; d <<= 1) mx = fmaxf(mx, __shfl_xor(mx, d));
    float sum = 0.f;
#pragma unroll
    for (int rr = 0; rr < 4; ++rr) sum += __expf(s0[rr] - mx) + __expf(s1[rr] - mx);
#pragma unroll
    for (int d = 1; d < 16; d <<= 1) sum += __shfl_xor(sum, d);
    float lse = mx + __logf(sum);
    int b = row0 + row;
    int tgt = text[b * L_ + losst];
    if ((tgt >> 3) == lp) {
      float lv = (tgt & 4) ? s1[tgt & 3] : s0[tgt & 3];
      float loss = (lse - lv) * (1.f / (float)L_);
      if (losst == 0) out[b] = loss;
      else out[b] += loss;
    }
    return;
  }

  // ---------------- LSTM gate GEMM + cell update
  const int s = blockIdx.x;                // gate cols [s*128, s*128+128)
  const int m0 = blockIdx.y * 128;
  const int wrow = m0 + wave * 32;
  const ushortT* Wf0 = Wfrag + (size_t)(2 * s) * 36864;       // slice stride 18*4*64*8
  const ushortT* Wf1 = Wf0 + 36864;

  f32x4 acc[2][8];
#pragma unroll
  for (int mi = 0; mi < 2; ++mi)
#pragma unroll
    for (int ni = 0; ni < 8; ++ni)
#pragma unroll
      for (int x = 0; x < 4; ++x) acc[mi][ni][x] = 0.f;

#pragma unroll
  for (int xk = 0; xk < 2; ++xk) {
    short8 a0 = *(const short8*)(&xs[(size_t)(wrow + r) * EP_ + xk * 32 + ak]);
    short8 a1 = *(const short8*)(&xs[(size_t)(wrow + 16 + r) * EP_ + xk * 32 + ak]);
#pragma unroll
    for (int ni = 0; ni < 8; ++ni) {
      const ushortT* Wf = (ni < 4) ? Wf0 : Wf1;
      short8 b = *(const short8*)(&Wf[(((16 + xk) * 4 + (ni & 3)) * 64 + lane) * 8]);
      acc[0][ni] = __builtin_amdgcn_mfma_f32_16x16x32_bf16(a0, b, acc[0][ni], 0, 0, 0);
      acc[1][ni] = __builtin_amdgcn_mfma_f32_16x16x32_bf16(a1, b, acc[1][ni], 0, 0, 0);
    }
  }
  if (hin) {
#pragma unroll 4
    for (int ks = 0; ks < 16; ++ks) {
      short8 a0 = *(const short8*)(&hin[(size_t)(wrow + r) * H_ + ks * 32 + ak]);
      short8 a1 = *(const short8*)(&hin[(size_t)(wrow + 16 + r) * H_ + ks * 32 + ak]);
#pragma unroll
      for (int ni = 0; ni < 8; ++ni) {
        const ushortT* Wf = (ni < 4) ? Wf0 : Wf1;
        short8 b = *(const short8*)(&Wf[((ks * 4 + (ni & 3)) * 64 + lane) * 8]);
        acc[0][ni] = __builtin_amdgcn_mfma_f32_16x16x32_bf16(a0, b, acc[0][ni], 0, 0, 0);
        acc[1][ni] = __builtin_amdgcn_mfma_f32_16x16x32_bf16(a1, b, acc[1][ni], 0, 0, 0);
      }
    }
  }

  // epilogue: shuffle-transpose + cell update
#pragma unroll
  for (int mi = 0; mi < 2; ++mi) {
    int row = wrow + mi * 16 + q * 4 + (r & 3);
#pragma unroll
    for (int ni = 0; ni < 8; ++ni) {
      float v0 = acc[mi][ni][0], v1 = acc[mi][ni][1], v2 = acc[mi][ni][2], v3 = acc[mi][ni][3];
      float s0 = __shfl_xor(v0, 2), s1 = __shfl_xor(v1, 2),
            s2 = __shfl_xor(v2, 2), s3 = __shfl_xor(v3, 2);
      float a0, a1, a2, a3;
      if (r & 2) { a0 = s2; a1 = s3; a2 = v2; a3 = v3; }
      else       { a0 = v0; a1 = v1; a2 = s0; a3 = s1; }
      float t0 = __shfl_xor(a0, 1), t1 = __shfl_xor(a1, 1),
            t2 = __shfl_xor(a2, 1), t3 = __shfl_xor(a3, 1);
      float g0, g1, g2, g3;
      if (r & 1) { g0 = t1; g1 = a1; g2 = t3; g3 = a3; }
      else       { g0 = a0; g1 = t0; g2 = a2; g3 = t2; }
      int j = s * 32 + (ni >> 2) * 16 + (ni & 3) * 4 + (r >> 2);
      f32x4 bb = *(const f32x4*)(&biasc[j * 4]);
      float si = sigm(g0 + bb[0]);
      float sf = sigm(g1 + bb[1]);
      float tg = tanh_f(g2 + bb[2]);
      float so = sigm(g3 + bb[3]);
      size_t ci = (size_t)row * H_ + j;
      float cprev = cconst ? 0.1f : c[ci];
      float cn = sf * cprev + si * tg;
      float hn = so * tanh_f(cn);
      c[ci] = cn;
      ushortT hb16 = f2bf(hn);
      hout[ci] = hb16;
      if (sel) {
        int len = lens[row];
        int eff = (len == 0) ? L_ : len;
        if (t == eff - 1) sel[ci] = hb16;
      }
    }
  }
}

// ================================================================ standalone decoder loss (final step)
__global__ __launch_bounds__(256)
void dec_loss3_k(const ushortT* __restrict__ h, const ushortT* __restrict__ Woutfrag,
                 const int* __restrict__ text, int t, float* __restrict__ out) {
  __shared__ float pbuf[4 * 16 * 132];
  const int tid = threadIdx.x;
  const int row0 = blockIdx.x * 16;
  const int lane = tid & 63, wave = tid >> 6;
  const int am = lane & 15, ak = (lane >> 4) * 8;

  f32x4 acc[8];
#pragma unroll
  for (int i = 0; i < 8; ++i)
#pragma unroll
    for (int r = 0; r < 4; ++r) acc[i][r] = 0.f;

#pragma unroll
  for (int ks = 0; ks < 4; ++ks) {
    int ksg = wave * 4 + ks;
    short8 a = *(const short8*)(&h[(size_t)(row0 + am) * H_ + ksg * 32 + ak]);
#pragma unroll
    for (int nf = 0; nf < 8; ++nf) {
      short8 b = *(const short8*)(&Woutfrag[((ksg * 8 + nf) * 64 + lane) * 8]);
      acc[nf] = __builtin_amdgcn_mfma_f32_16x16x32_bf16(a, b, acc[nf], 0, 0, 0);
    }
  }
#pragma unroll
  for (int nf = 0; nf < 8; ++nf)
#pragma unroll
    for (int r = 0; r < 4; ++r) {
      int rowL = (lane >> 4) * 4 + r;
      pbuf[(wave * 16 + rowL) * 132 + nf * 16 + am] = acc[nf][r];
    }
  __syncthreads();

  int row = tid >> 4, lp = tid & 15;
  f32x4 s0, s1;
#pragma unroll
  for (int r = 0; r < 4; ++r) { s0[r] = 0.f; s1[r] = 0.f; }
#pragma unroll
  for (int wv = 0; wv < 4; ++wv) {
    s0 += *(const f32x4*)(&pbuf[(wv * 16 + row) * 132 + lp * 8]);
    s1 += *(const f32x4*)(&pbuf[(wv * 16 + row) * 132 + lp * 8 + 4]);
  }
  float mx = s0[0];
#pragma unroll
  for (int r = 1; r < 4; ++r) mx = fmaxf(mx, s0[r]);
#pragma unroll
  for (int r = 0; r < 4; ++r) mx = fmaxf(mx, s1[r]);
#pragma unroll
  for (int d = 1; d < 16; d <<= 1) mx = fmaxf(mx, __shfl_xor(mx, d));
  float sum = 0.f;
#pragma unroll
  for (int r = 0; r < 4; ++r) sum += __expf(s0[r] - mx) + __expf(s1[r] - mx);
#pragma unroll
  for (int d = 1; d < 16; d <<= 1) sum += __shfl_xor(sum, d);
  float lse = mx + __logf(sum);
  int b = row0 + row;
  int tgt = text[b * L_ + t];
  if ((tgt >> 3) == lp) {
    float lv = (tgt & 4) ? s1[tgt & 3] : s0[tgt & 3];
    float loss = (lse - lv) * (1.f / (float)L_);
    if (t == 0) out[b] = loss;
    else out[b] += loss;
  }
}

// ================================================================ softmax / transpose
__global__ __launch_bounds__(256)
void softmax_bf_rows_k(ushortT* __restrict__ P) {
  int rr = blockIdx.x, tid = threadIdx.x;
  ushortT* row = P + (size_t)rr * B_;
  float xv[16];
  float m = -1e30f;
#pragma unroll
  for (int l = 0; l < 16; ++l) { float v = bf2f(row[tid + l * 256]); xv[l] = v; m = fmaxf(m, v); }
  __shared__ float red[256];
  red[tid] = m; __syncthreads();
  for (int st = 128; st > 0; st >>= 1) { if (tid < st) red[tid] = fmaxf(red[tid], red[tid + st]); __syncthreads(); }
  m = red[0]; __syncthreads();
  float s = 0.f;
#pragma unroll
  for (int l = 0; l < 16; ++l) { float e = __expf(xv[l] - m); xv[l] = e; s += e; }
  red[tid] = s; __syncthreads();
  for (int st = 128; st > 0; st >>= 1) { if (tid < st) red[tid] += red[tid + st]; __syncthreads(); }
  float inv = 1.f / red[0];
#pragma unroll
  for (int l = 0; l < 16; ++l) row[tid + l * 256] = f2bf(xv[l] * inv);
}

__global__ void transpose_bf_k(const ushortT* __restrict__ in, ushortT* __restrict__ out,
                               int R, int Ccols) {
  __shared__ ushortT tile[32][33];
  int c0 = blockIdx.x * 32, r0 = blockIdx.y * 32;
  int tx = threadIdx.x & 31, ty = threadIdx.x >> 5;
  for (int i = ty; i < 32; i += 8) tile[i][tx] = in[(size_t)(r0 + i) * Ccols + c0 + tx];
  __syncthreads();
  for (int i = ty; i < 32; i += 8) out[(size_t)(c0 + i) * R + r0 + tx] = tile[tx][i];
}

// ================================================================ launch
extern "C" void kernel_launch(void* const* d_in, const int* in_sizes, int n_in,
                              void* d_out, int out_size, void* d_ws, size_t ws_size,
                              hipStream_t stream) {
  const float* visual = (const float*)d_in[0];
  const int*   text   = (const int*)  d_in[1];
  const float* emb    = (const float*)d_in[2];
  const float* W_ih   = (const float*)d_in[3];
  const float* W_hh   = (const float*)d_in[4];
  const float* b_ih   = (const float*)d_in[5];
  const float* b_hh   = (const float*)d_in[6];
  const float* W_enc  = (const float*)d_in[7];
  const float* b_enc  = (const float*)d_in[8];
  const float* W_out  = (const float*)d_in[9];
  const float* W_vis  = (const float*)d_in[10];
  float* out = (float*)d_out;

  char* w = (char*)d_ws;
  auto alloc = [&](size_t bytes) { char* p = w; w += (bytes + 255) & ~(size_t)255; return p; };
  ushortT* xs_enc   = (ushortT*)alloc((size_t)L_ * B_ * EP_ * 2);
  ushortT* xs_dec   = (ushortT*)alloc((size_t)L_ * B_ * EP_ * 2);
  ushortT* Wfrag    = (ushortT*)alloc((size_t)32 * 18 * 4 * 64 * 8 * 2);   // 2.25 MB
  ushortT* Woutfrag = (ushortT*)alloc((size_t)16 * 8 * 64 * 8 * 2);        // 128 KB
  float*   biasc    = (float*)  alloc((size_t)G4_ * 4);
  float*   biasc0   = (float*)  alloc((size_t)G4_ * 4);
  ushortT* Wvisbf   = (ushortT*)alloc((size_t)H_ * VIS_ * 2);
  ushortT* Wencbf   = (ushortT*)alloc((size_t)H_ * H_ * 2);
  ushortT* visbf    = (ushortT*)alloc((size_t)B_ * VIS_ * 2);
  ushortT* henc0    = (ushortT*)alloc((size_t)B_ * H_ * 2);
  ushortT* henc1    = (ushortT*)alloc((size_t)B_ * H_ * 2);
  float*   cenc     = (float*)  alloc((size_t)B_ * H_ * 4);
  ushortT* selbf    = (ushortT*)alloc((size_t)B_ * H_ * 2);
  ushortT* vbf      = (ushortT*)alloc((size_t)B_ * H_ * 2);
  ushortT* tencbf   = (ushortT*)alloc((size_t)B_ * H_ * 2);
  ushortT* Pbf      = (ushortT*)alloc((size_t)B_ * B_ * 2);
  ushortT* Vtbf     = (ushortT*)alloc((size_t)H_ * B_ * 2);
  float*   cdec     = (float*)  alloc((size_t)B_ * H_ * 4);
  ushortT* hdec0    = (ushortT*)alloc((size_t)B_ * H_ * 2);
  ushortT* hdec1    = (ushortT*)alloc((size_t)B_ * H_ * 2);
  int*     lens     = (int*)    alloc((size_t)B_ * 4);
  float*   parts    = (float*)  alloc((size_t)8 * B_ * H_ * 4);

  // ---- mega prep
  prep_all_k<<<dim3(30832), dim3(256), 0, stream>>>(
      visual, text, emb, W_ih, W_hh, b_ih, b_hh, W_enc, W_out, W_vis,
      xs_enc, xs_dec, Wfrag, Woutfrag, biasc, biasc0,
      Wvisbf, Wencbf, visbf, lens);

  // ---- visual projection (z=4, kchunk=512) + rownorm -> vbf
  gemm_ws_k<<<dim3(H_ / 64, B_ / 256, 4), dim3(256), 0, stream>>>(
      visbf, VIS_, Wvisbf, VIS_, 512, parts, nullptr, H_, B_);
  reduce_norm_k<<<dim3(B_), dim3(256), 0, stream>>>(parts, 4, nullptr, 0, vbf, nullptr);

  // ---- encoder LSTM (t=0 folds h0 into biasc0)
  for (int t = 0; t < L_; ++t) {
    const ushortT* hin = (t == 0) ? nullptr : ((t & 1) ? henc1 : henc0);
    ushortT* hout = (t & 1) ? henc0 : henc1;
    lstm4_k<<<dim3(16, 32), dim3(256), 0, stream>>>(
        hin, Wfrag, xs_enc + (size_t)t * B_ * EP_,
        (t == 0) ? biasc0 : biasc, cenc, (t == 0) ? 1 : 0,
        hout, selbf, lens, t, nullptr, nullptr, nullptr, -1);
  }

  // ---- enc linear (z=1) + bias/relu/rownorm -> tencbf
  gemm_ws_k<<<dim3(H_ / 64, B_ / 256, 1), dim3(256), 0, stream>>>(
      selbf, H_, Wencbf, H_, 512, parts, nullptr, H_, B_);
  reduce_norm_k<<<dim3(B_), dim3(256), 0, stream>>>(parts, 1, b_enc, 1, tencbf, nullptr);

  // ---- attention
  gemm_ws_k<<<dim3(B_ / 64, B_ / 256, 1), dim3(256), 0, stream>>>(
      tencbf, H_, vbf, H_, 512, nullptr, Pbf, B_, B_);
  softmax_bf_rows_k<<<dim3(B_), dim3(256), 0, stream>>>(Pbf);
  transpose_bf_k<<<dim3(H_ / 32, B_ / 32), dim3(256), 0, stream>>>(vbf, Vtbf, B_, H_);
  gemm_ws_k<<<dim3(H_ / 64, B_ / 256, 4), dim3(256), 0, stream>>>(
      Pbf, B_, Vtbf, B_, 1024, parts, nullptr, H_, B_);
  reduce_norm_k<<<dim3(B_), dim3(256), 0, stream>>>(parts, 4, nullptr, 0, hdec0, cdec);

  // ---- decoder LSTM with fused previous-step NLL (t>=1), final NLL standalone
  for (int t = 0; t < L_; ++t) {
    const ushortT* hin = (t & 1) ? hdec1 : hdec0;
    ushortT* hout = (t & 1) ? hdec0 : hdec1;
    dim3 grid = (t > 0) ? dim3(24, 32) : dim3(16, 32);
    lstm4_k<<<grid, dim3(256), 0, stream>>>(
        hin, Wfrag, xs_dec + (size_t)t * B_ * EP_,
        biasc, cdec, 0, hout, nullptr, nullptr, t,
        Woutfrag, text, out, t - 1);
  }
  // h_15 lives in hdec0 (t=15 odd -> hout = hdec0)
  dec_loss3_k<<<dim3(B_ / 16), dim3(256), 0, stream>>>(hdec0, Woutfrag, text, L_ - 1, out);
}

// Round 10
// 1156.361 us; speedup vs baseline: 3.6964x; 1.1850x over previous
//
#include <hip/hip_runtime.h>
#include <math.h>

#define B_    4096
#define L_    16
#define E_    50
#define EP_   64
#define H_    512
#define G4_   2048
#define V_    128
#define VIS_  2048

typedef unsigned short ushortT;
typedef ushortT ushort8 __attribute__((ext_vector_type(8)));
typedef ushortT ushort4v __attribute__((ext_vector_type(4)));
typedef short   short8  __attribute__((ext_vector_type(8)));
typedef float   f32x4   __attribute__((ext_vector_type(4)));

__device__ __forceinline__ ushortT f2bf(float f) {
  union { float f; unsigned u; } v; v.f = f;
  unsigned u = v.u;
  u += 0x7fffu + ((u >> 16) & 1u);
  return (ushortT)(u >> 16);
}
__device__ __forceinline__ float bf2f(ushortT h) {
  union { unsigned u; float f; } v; v.u = ((unsigned)h) << 16;
  return v.f;
}
__device__ __forceinline__ float sigm(float x) { return 1.f / (1.f + __expf(-x)); }
__device__ __forceinline__ float tanh_f(float x) { return 1.f - 2.f / (__expf(2.f * x) + 1.f); }

// ================================================================ mega prep (grid 30832 x 256)
__global__ void prep_all_k(const float* __restrict__ visual, const int* __restrict__ text,
                           const float* __restrict__ emb,
                           const float* __restrict__ W_ih, const float* __restrict__ W_hh,
                           const float* __restrict__ b_ih, const float* __restrict__ b_hh,
                           const float* __restrict__ W_enc, const float* __restrict__ W_out,
                           const float* __restrict__ W_vis,
                           ushortT* __restrict__ xs_enc, ushortT* __restrict__ xs_dec,
                           ushortT* __restrict__ Wfrag, ushortT* __restrict__ Woutfrag,
                           float* __restrict__ biasc, float* __restrict__ biasc0,
                           ushortT* __restrict__ Wvisbf, ushortT* __restrict__ Wencbf,
                           ushortT* __restrict__ visbf, int* __restrict__ lens) {
  int bid = blockIdx.x, tid = threadIdx.x;
  if (bid < 16384) {
    int idx = bid * 256 + tid;
    int e = idx & 63, r = idx >> 6, b = r % B_, t = r / B_;
    ushortT ve = 0, vd = 0;
    if (e < E_) {
      int ie = text[b * L_ + t];
      int id = (t == 0) ? 0 : text[b * L_ + t - 1];
      ve = f2bf(emb[ie * E_ + e]);
      vd = f2bf(emb[id * E_ + e]);
    }
    xs_enc[idx] = ve; xs_dec[idx] = vd;
  } else if (bid < 16960) {                           // Wfrag: 32 slices x 18 ks x 4 ni x 64 ln
    int idx8 = (bid - 16384) * 256 + tid;
    int s = idx8 / 4608;
    int rem = idx8 - s * 4608;
    int ks = rem >> 8;
    int rem2 = rem & 255;
    int ni = rem2 >> 6, ln = rem2 & 63;
    int row = s * 64 + ni * 16 + (ln & 15);
    int kc = (ln >> 4) * 8;
    int j = row >> 2, qg = row & 3;
    int srow = qg * H_ + j;
    ushort8 val;
    if (ks < 16) {
      const float* src = W_hh + (size_t)srow * H_ + ks * 32 + kc;
#pragma unroll
      for (int x = 0; x < 8; ++x) val[x] = f2bf(src[x]);
    } else {
      int kb = (ks - 16) * 32 + kc;
#pragma unroll
      for (int x = 0; x < 8; ++x)
        val[x] = (kb + x < E_) ? f2bf(W_ih[(size_t)srow * E_ + kb + x]) : (ushortT)0;
    }
    *(ushort8*)(&Wfrag[(size_t)idx8 * 8]) = val;
  } else if (bid < 16992) {                           // Woutfrag
    int idx8 = (bid - 16960) * 256 + tid;
    int ks = idx8 >> 9;
    int rem = idx8 & 511;
    int nf = rem >> 6, ln = rem & 63;
    int row = nf * 16 + (ln & 15);
    int kc = ks * 32 + (ln >> 4) * 8;
    const float* src = W_out + (size_t)row * H_ + kc;
    ushort8 val;
#pragma unroll
    for (int x = 0; x < 8; ++x) val[x] = f2bf(src[x]);
    *(ushort8*)(&Woutfrag[(size_t)idx8 * 8]) = val;
  } else if (bid < 21088) {
    int idx = (bid - 16992) * 256 + tid;
    Wvisbf[idx] = f2bf(W_vis[idx]);
  } else if (bid < 22112) {
    int idx = (bid - 21088) * 256 + tid;
    Wencbf[idx] = f2bf(W_enc[idx]);
  } else if (bid < 30304) {
    int i = (bid - 22112) * 256 + tid;
    float4 v = ((const float4*)visual)[i];
    ushort4v o;
    o[0] = f2bf(v.x); o[1] = f2bf(v.y); o[2] = f2bf(v.z); o[3] = f2bf(v.w);
    ((ushort4v*)visbf)[i] = o;
  } else if (bid < 30320) {
    int b = (bid - 30304) * 256 + tid;
    int c = 0;
    for (int t = 0; t < L_; ++t) c += (text[b * L_ + t] != 0) ? 1 : 0;
    lens[b] = c;
  } else {                                            // biasc / biasc0, one wave per gate-row
    int wave = tid >> 6, lane = tid & 63;
    int p = (bid - 30320) * 4 + wave;
    int j = p >> 2, q = p & 3, o = q * H_ + j;
    const float* wr = W_hh + (size_t)o * H_;
    float rs = 0.f;
#pragma unroll
    for (int k = 0; k < H_ / 64; ++k) rs += wr[lane + k * 64];
#pragma unroll
    for (int d = 1; d < 64; d <<= 1) rs += __shfl_xor(rs, d);
    if (lane == 0) {
      float base = b_ih[o] + b_hh[o];
      biasc[p] = base;
      biasc0[p] = base + 0.1f * rs;
    }
  }
}

// ================================================================ weights-slice GEMM (+kchunk)
__global__ __launch_bounds__(256, 2)
void gemm_ws_k(const ushortT* __restrict__ A, int lda,
               const ushortT* __restrict__ B, int ldb, int kchunk,
               float* __restrict__ Cf, ushortT* __restrict__ Cb,
               int ldc, int Mtot) {
  __shared__ ushortT wlds[64 * 512];
  const int tid = threadIdx.x;
  const int n0 = blockIdx.x * 64;
  const int m0 = blockIdx.y * 256;
  const int kbeg0 = blockIdx.z * kchunk;
  const int lane = tid & 63, wave = tid >> 6;
  const int am = lane & 15, ak = (lane >> 4) * 8;
  const int wrow = m0 + wave * 64;

  f32x4 acc[4][4];
#pragma unroll
  for (int i = 0; i < 4; ++i)
#pragma unroll
    for (int j = 0; j < 4; ++j)
#pragma unroll
      for (int r = 0; r < 4; ++r) acc[i][j][r] = 0.f;

  for (int kb = kbeg0; kb < kbeg0 + kchunk; kb += 512) {
#pragma unroll
    for (int i = 0; i < 16; ++i) {
      int idx = i * 256 + tid;
      int ks = idx >> 8;
      int rem = idx & 255;
      int ni = rem >> 6, ln = rem & 63;
      int row = n0 + ni * 16 + (ln & 15);
      int kc = (ln >> 4) * 8;
      *(ushort8*)(&wlds[idx * 8]) = *(const ushort8*)(&B[(size_t)row * ldb + kb + ks * 32 + kc]);
    }
    __syncthreads();
#pragma unroll 4
    for (int ks = 0; ks < 16; ++ks) {
      short8 a[4];
#pragma unroll
      for (int mi = 0; mi < 4; ++mi)
        a[mi] = *(const short8*)(&A[(size_t)(wrow + mi * 16 + am) * lda + kb + ks * 32 + ak]);
#pragma unroll
      for (int ni = 0; ni < 4; ++ni) {
        short8 b = *(const short8*)(&wlds[((ks * 4 + ni) * 64 + lane) * 8]);
#pragma unroll
        for (int mi = 0; mi < 4; ++mi)
          acc[mi][ni] = __builtin_amdgcn_mfma_f32_16x16x32_bf16(a[mi], b, acc[mi][ni], 0, 0, 0);
      }
    }
    __syncthreads();
  }

  if (Cb) {
#pragma unroll
    for (int mi = 0; mi < 4; ++mi)
#pragma unroll
      for (int r = 0; r < 4; ++r) {
        int m = wrow + mi * 16 + (lane >> 4) * 4 + r;
#pragma unroll
        for (int ni = 0; ni < 4; ++ni)
          Cb[(size_t)m * ldc + n0 + ni * 16 + am] = f2bf(acc[mi][ni][r]);
      }
  } else {
    float* Cz = Cf + (size_t)blockIdx.z * Mtot * ldc;
#pragma unroll
    for (int mi = 0; mi < 4; ++mi)
#pragma unroll
      for (int r = 0; r < 4; ++r) {
        int m = wrow + mi * 16 + (lane >> 4) * 4 + r;
#pragma unroll
        for (int ni = 0; ni < 4; ++ni)
          Cz[(size_t)m * ldc + n0 + ni * 16 + am] = acc[mi][ni][r];
      }
  }
}

// ================================================================ reduce partials + bias/relu + rownorm
__global__ void reduce_norm_k(const float* __restrict__ parts, int nparts,
                              const float* __restrict__ bias, int relu,
                              ushortT* __restrict__ outb, float* __restrict__ outc) {
  int b = blockIdx.x, tid = threadIdx.x;
  float v[2];
  float ss = 0.f;
#pragma unroll
  for (int l = 0; l < 2; ++l) {
    int i = tid + l * 256;
    float s = 0.f;
    for (int p = 0; p < nparts; ++p)
      s += parts[(size_t)p * B_ * H_ + (size_t)b * H_ + i];
    if (bias) s += bias[i];
    if (relu) s = fmaxf(s, 0.f);
    v[l] = s;
    ss += s * s;
  }
  __shared__ float red[256];
  red[tid] = ss; __syncthreads();
  for (int st = 128; st > 0; st >>= 1) { if (tid < st) red[tid] += red[tid + st]; __syncthreads(); }
  float inv = 1.f / sqrtf(red[0]);
#pragma unroll
  for (int l = 0; l < 2; ++l) {
    int i = tid + l * 256;
    float x = v[l] * inv;
    outb[(size_t)b * H_ + i] = f2bf(x);
    if (outc) outc[(size_t)b * H_ + i] = x;
  }
}

// ================================================================ lstm5: 512 threads, 8 waves,
// wave = 16 rows x 128 gate-cols; B-frags double-buffered in LDS (24 KB window);
// fused previous-step NLL for blockIdx.x >= 16 (decoder, two 4-wave groups of 16 rows).
__global__ __launch_bounds__(512, 2)
void lstm5_k(const ushortT* __restrict__ hin, const ushortT* __restrict__ Wfrag,
             const ushortT* __restrict__ xs, const float* __restrict__ biasc,
             float* __restrict__ c, int cconst,
             ushortT* __restrict__ hout, ushortT* __restrict__ sel,
             const int* __restrict__ lens, int t,
             const ushortT* __restrict__ Woutfrag, const int* __restrict__ text,
             float* __restrict__ out, int losst) {
  __shared__ char smem[67584];                 // lstm: 2x24576 B wl; loss: 2x8448 fp32 pbuf
  const int tid = threadIdx.x;
  const int lane = tid & 63, wave = tid >> 6;
  const int q = lane >> 4, r = lane & 15;
  const int ak = q * 8;

  if (blockIdx.x >= 16) {
    // ---------------- fused NLL for previous step's h (= hin); two 4-wave groups x 16 rows
    float* pbuf = (float*)smem;
    const int group = wave >> 2, wv = wave & 3;
    float* pbase = pbuf + group * 8448;
    const int row0g = blockIdx.y * 128 + (blockIdx.x - 16) * 32 + group * 16;
    f32x4 dacc[8];
#pragma unroll
    for (int i = 0; i < 8; ++i)
#pragma unroll
      for (int x = 0; x < 4; ++x) dacc[i][x] = 0.f;
#pragma unroll
    for (int ks = 0; ks < 4; ++ks) {
      int ksg = wv * 4 + ks;
      short8 a = *(const short8*)(&hin[(size_t)(row0g + r) * H_ + ksg * 32 + ak]);
#pragma unroll
      for (int nf = 0; nf < 8; ++nf) {
        short8 b = *(const short8*)(&Woutfrag[((ksg * 8 + nf) * 64 + lane) * 8]);
        dacc[nf] = __builtin_amdgcn_mfma_f32_16x16x32_bf16(a, b, dacc[nf], 0, 0, 0);
      }
    }
#pragma unroll
    for (int nf = 0; nf < 8; ++nf)
#pragma unroll
      for (int rr = 0; rr < 4; ++rr)
        pbase[(wv * 16 + q * 4 + rr) * 132 + nf * 16 + r] = dacc[nf][rr];
    __syncthreads();
    int g = tid & 255;
    int grp2 = tid >> 8;
    float* pb2 = pbuf + grp2 * 8448;
    int row = g >> 4, lp = g & 15;
    f32x4 s0, s1;
#pragma unroll
    for (int rr = 0; rr < 4; ++rr) { s0[rr] = 0.f; s1[rr] = 0.f; }
#pragma unroll
    for (int wv2 = 0; wv2 < 4; ++wv2) {
      s0 += *(const f32x4*)(&pb2[(wv2 * 16 + row) * 132 + lp * 8]);
      s1 += *(const f32x4*)(&pb2[(wv2 * 16 + row) * 132 + lp * 8 + 4]);
    }
    float mx = s0[0];
#pragma unroll
    for (int rr = 1; rr < 4; ++rr) mx = fmaxf(mx, s0[rr]);
#pragma unroll
    for (int rr = 0; rr < 4; ++rr) mx = fmaxf(mx, s1[rr]);
#pragma unroll
    for (int d = 1; d < 16; d <<= 1) mx = fmaxf(mx, __shfl_xor(mx, d));
    float sum = 0.f;
#pragma unroll
    for (int rr = 0; rr < 4; ++rr) sum += __expf(s0[rr] - mx) + __expf(s1[rr] - mx);
#pragma unroll
    for (int d = 1; d < 16; d <<= 1) sum += __shfl_xor(sum, d);
    float lse = mx + __logf(sum);
    int b = blockIdx.y * 128 + (blockIdx.x - 16) * 32 + grp2 * 16 + row;
    int tgt = text[b * L_ + losst];
    if ((tgt >> 3) == lp) {
      float lv = (tgt & 4) ? s1[tgt & 3] : s0[tgt & 3];
      float loss = (lse - lv) * (1.f / (float)L_);
      if (losst == 0) out[b] = loss;
      else out[b] += loss;
    }
    return;
  }

  // ---------------- LSTM gate GEMM + cell update
  ushortT* wl = (ushortT*)smem;                // two 12288-elem buffers
  const int s2 = blockIdx.x;                   // gate cols [s2*128, +128)
  const int m0 = blockIdx.y * 128;
  const int wrow = m0 + wave * 16;
  const ushortT* Wbase = Wfrag + (size_t)(2 * s2) * 36864;

  auto stage = [&](int chunk, int buf) {
#pragma unroll
    for (int i = 0; i < 3; ++i) {
      int u = tid + i * 512;                   // 0..1535
      int f = u >> 6, l = u & 63;
      int kk = f >> 3, nn = f & 7;
      int ks = chunk * 3 + kk;
      const ushortT* src = Wbase + (size_t)(nn >> 2) * 36864 + ((size_t)(ks * 4 + (nn & 3)) * 64 + l) * 8;
      *(ushort8*)(&wl[(size_t)buf * 12288 + ((kk * 8 + nn) * 64 + l) * 8]) = *(const ushort8*)src;
    }
  };

  f32x4 acc[8];
#pragma unroll
  for (int nn = 0; nn < 8; ++nn)
#pragma unroll
    for (int x = 0; x < 4; ++x) acc[nn][x] = 0.f;

  const int cstart = hin ? 0 : 5;
  stage(cstart, 0);
  __syncthreads();
  for (int ch = cstart; ch < 6; ++ch) {
    int buf = (ch - cstart) & 1;
    if (ch < 5) stage(ch + 1, buf ^ 1);
#pragma unroll
    for (int kk = 0; kk < 3; ++kk) {
      int ks = ch * 3 + kk;
      if (!hin && ks < 16) continue;
      short8 a;
      if (ks < 16) a = *(const short8*)(&hin[(size_t)(wrow + r) * H_ + ks * 32 + ak]);
      else         a = *(const short8*)(&xs[(size_t)(wrow + r) * EP_ + (ks - 16) * 32 + ak]);
#pragma unroll
      for (int nn = 0; nn < 8; ++nn) {
        short8 b = *(const short8*)(&wl[(size_t)buf * 12288 + ((kk * 8 + nn) * 64 + lane) * 8]);
        acc[nn] = __builtin_amdgcn_mfma_f32_16x16x32_bf16(a, b, acc[nn], 0, 0, 0);
      }
    }
    __syncthreads();
  }

  // epilogue: shuffle-transpose (verified) + cell update; 16 rows x 128 cols per wave
#pragma unroll
  for (int nn = 0; nn < 8; ++nn) {
    int row = wrow + q * 4 + (r & 3);
    float v0 = acc[nn][0], v1 = acc[nn][1], v2 = acc[nn][2], v3 = acc[nn][3];
    float s0 = __shfl_xor(v0, 2), s1 = __shfl_xor(v1, 2),
          s2s = __shfl_xor(v2, 2), s3 = __shfl_xor(v3, 2);
    float a0, a1, a2, a3;
    if (r & 2) { a0 = s2s; a1 = s3; a2 = v2; a3 = v3; }
    else       { a0 = v0; a1 = v1; a2 = s0; a3 = s1; }
    float t0 = __shfl_xor(a0, 1), t1 = __shfl_xor(a1, 1),
          t2 = __shfl_xor(a2, 1), t3 = __shfl_xor(a3, 1);
    float g0, g1, g2, g3;
    if (r & 1) { g0 = t1; g1 = a1; g2 = t3; g3 = a3; }
    else       { g0 = a0; g1 = t0; g2 = a2; g3 = t2; }
    int j = s2 * 32 + nn * 4 + (r >> 2);
    f32x4 bb = *(const f32x4*)(&biasc[j * 4]);
    float si = sigm(g0 + bb[0]);
    float sf = sigm(g1 + bb[1]);
    float tg = tanh_f(g2 + bb[2]);
    float so = sigm(g3 + bb[3]);
    size_t ci = (size_t)row * H_ + j;
    float cprev = cconst ? 0.1f : c[ci];
    float cn = sf * cprev + si * tg;
    float hn = so * tanh_f(cn);
    c[ci] = cn;
    ushortT hb16 = f2bf(hn);
    hout[ci] = hb16;
    if (sel) {
      int len = lens[row];
      int eff = (len == 0) ? L_ : len;
      if (t == eff - 1) sel[ci] = hb16;
    }
  }
}

// ================================================================ standalone decoder loss (final step)
__global__ __launch_bounds__(256)
void dec_loss3_k(const ushortT* __restrict__ h, const ushortT* __restrict__ Woutfrag,
                 const int* __restrict__ text, int t, float* __restrict__ out) {
  __shared__ float pbuf[4 * 16 * 132];
  const int tid = threadIdx.x;
  const int row0 = blockIdx.x * 16;
  const int lane = tid & 63, wave = tid >> 6;
  const int am = lane & 15, ak = (lane >> 4) * 8;

  f32x4 acc[8];
#pragma unroll
  for (int i = 0; i < 8; ++i)
#pragma unroll
    for (int r = 0; r < 4; ++r) acc[i][r] = 0.f;

#pragma unroll
  for (int ks = 0; ks < 4; ++ks) {
    int ksg = wave * 4 + ks;
    short8 a = *(const short8*)(&h[(size_t)(row0 + am) * H_ + ksg * 32 + ak]);
#pragma unroll
    for (int nf = 0; nf < 8; ++nf) {
      short8 b = *(const short8*)(&Woutfrag[((ksg * 8 + nf) * 64 + lane) * 8]);
      acc[nf] = __builtin_amdgcn_mfma_f32_16x16x32_bf16(a, b, acc[nf], 0, 0, 0);
    }
  }
#pragma unroll
  for (int nf = 0; nf < 8; ++nf)
#pragma unroll
    for (int r = 0; r < 4; ++r) {
      int rowL = (lane >> 4) * 4 + r;
      pbuf[(wave * 16 + rowL) * 132 + nf * 16 + am] = acc[nf][r];
    }
  __syncthreads();

  int row = tid >> 4, lp = tid & 15;
  f32x4 s0, s1;
#pragma unroll
  for (int r = 0; r < 4; ++r) { s0[r] = 0.f; s1[r] = 0.f; }
#pragma unroll
  for (int wv = 0; wv < 4; ++wv) {
    s0 += *(const f32x4*)(&pbuf[(wv * 16 + row) * 132 + lp * 8]);
    s1 += *(const f32x4*)(&pbuf[(wv * 16 + row) * 132 + lp * 8 + 4]);
  }
  float mx = s0[0];
#pragma unroll
  for (int r = 1; r < 4; ++r) mx = fmaxf(mx, s0[r]);
#pragma unroll
  for (int r = 0; r < 4; ++r) mx = fmaxf(mx, s1[r]);
#pragma unroll
  for (int d = 1; d < 16; d <<= 1) mx = fmaxf(mx, __shfl_xor(mx, d));
  float sum = 0.f;
#pragma unroll
  for (int r = 0; r < 4; ++r) sum += __expf(s0[r] - mx) + __expf(s1[r] - mx);
#pragma unroll
  for (int d = 1; d < 16; d <<= 1) sum += __shfl_xor(sum, d);
  float lse = mx + __logf(sum);
  int b = row0 + row;
  int tgt = text[b * L_ + t];
  if ((tgt >> 3) == lp) {
    float lv = (tgt & 4) ? s1[tgt & 3] : s0[tgt & 3];
    float loss = (lse - lv) * (1.f / (float)L_);
    if (t == 0) out[b] = loss;
    else out[b] += loss;
  }
}

// ================================================================ softmax / transpose
__global__ __launch_bounds__(256)
void softmax_bf_rows_k(ushortT* __restrict__ P) {
  int rr = blockIdx.x, tid = threadIdx.x;
  ushortT* row = P + (size_t)rr * B_;
  float xv[16];
  float m = -1e30f;
#pragma unroll
  for (int l = 0; l < 16; ++l) { float v = bf2f(row[tid + l * 256]); xv[l] = v; m = fmaxf(m, v); }
  __shared__ float red[256];
  red[tid] = m; __syncthreads();
  for (int st = 128; st > 0; st >>= 1) { if (tid < st) red[tid] = fmaxf(red[tid], red[tid + st]); __syncthreads(); }
  m = red[0]; __syncthreads();
  float s = 0.f;
#pragma unroll
  for (int l = 0; l < 16; ++l) { float e = __expf(xv[l] - m); xv[l] = e; s += e; }
  red[tid] = s; __syncthreads();
  for (int st = 128; st > 0; st >>= 1) { if (tid < st) red[tid] += red[tid + st]; __syncthreads(); }
  float inv = 1.f / red[0];
#pragma unroll
  for (int l = 0; l < 16; ++l) row[tid + l * 256] = f2bf(xv[l] * inv);
}

__global__ void transpose_bf_k(const ushortT* __restrict__ in, ushortT* __restrict__ out,
                               int R, int Ccols) {
  __shared__ ushortT tile[32][33];
  int c0 = blockIdx.x * 32, r0 = blockIdx.y * 32;
  int tx = threadIdx.x & 31, ty = threadIdx.x >> 5;
  for (int i = ty; i < 32; i += 8) tile[i][tx] = in[(size_t)(r0 + i) * Ccols + c0 + tx];
  __syncthreads();
  for (int i = ty; i < 32; i += 8) out[(size_t)(c0 + i) * R + r0 + tx] = tile[tx][i];
}

// ================================================================ launch
extern "C" void kernel_launch(void* const* d_in, const int* in_sizes, int n_in,
                              void* d_out, int out_size, void* d_ws, size_t ws_size,
                              hipStream_t stream) {
  const float* visual = (const float*)d_in[0];
  const int*   text   = (const int*)  d_in[1];
  const float* emb    = (const float*)d_in[2];
  const float* W_ih   = (const float*)d_in[3];
  const float* W_hh   = (const float*)d_in[4];
  const float* b_ih   = (const float*)d_in[5];
  const float* b_hh   = (const float*)d_in[6];
  const float* W_enc  = (const float*)d_in[7];
  const float* b_enc  = (const float*)d_in[8];
  const float* W_out  = (const float*)d_in[9];
  const float* W_vis  = (const float*)d_in[10];
  float* out = (float*)d_out;

  char* w = (char*)d_ws;
  auto alloc = [&](size_t bytes) { char* p = w; w += (bytes + 255) & ~(size_t)255; return p; };
  ushortT* xs_enc   = (ushortT*)alloc((size_t)L_ * B_ * EP_ * 2);
  ushortT* xs_dec   = (ushortT*)alloc((size_t)L_ * B_ * EP_ * 2);
  ushortT* Wfrag    = (ushortT*)alloc((size_t)32 * 18 * 4 * 64 * 8 * 2);
  ushortT* Woutfrag = (ushortT*)alloc((size_t)16 * 8 * 64 * 8 * 2);
  float*   biasc    = (float*)  alloc((size_t)G4_ * 4);
  float*   biasc0   = (float*)  alloc((size_t)G4_ * 4);
  ushortT* Wvisbf   = (ushortT*)alloc((size_t)H_ * VIS_ * 2);
  ushortT* Wencbf   = (ushortT*)alloc((size_t)H_ * H_ * 2);
  ushortT* visbf    = (ushortT*)alloc((size_t)B_ * VIS_ * 2);
  ushortT* henc0    = (ushortT*)alloc((size_t)B_ * H_ * 2);
  ushortT* henc1    = (ushortT*)alloc((size_t)B_ * H_ * 2);
  float*   cenc     = (float*)  alloc((size_t)B_ * H_ * 4);
  ushortT* selbf    = (ushortT*)alloc((size_t)B_ * H_ * 2);
  ushortT* vbf      = (ushortT*)alloc((size_t)B_ * H_ * 2);
  ushortT* tencbf   = (ushortT*)alloc((size_t)B_ * H_ * 2);
  ushortT* Pbf      = (ushortT*)alloc((size_t)B_ * B_ * 2);
  ushortT* Vtbf     = (ushortT*)alloc((size_t)H_ * B_ * 2);
  float*   cdec     = (float*)  alloc((size_t)B_ * H_ * 4);
  ushortT* hdec0    = (ushortT*)alloc((size_t)B_ * H_ * 2);
  ushortT* hdec1    = (ushortT*)alloc((size_t)B_ * H_ * 2);
  int*     lens     = (int*)    alloc((size_t)B_ * 4);
  float*   parts    = (float*)  alloc((size_t)8 * B_ * H_ * 4);

  // ---- mega prep
  prep_all_k<<<dim3(30832), dim3(256), 0, stream>>>(
      visual, text, emb, W_ih, W_hh, b_ih, b_hh, W_enc, W_out, W_vis,
      xs_enc, xs_dec, Wfrag, Woutfrag, biasc, biasc0,
      Wvisbf, Wencbf, visbf, lens);

  // ---- visual projection (z=4) + rownorm -> vbf
  gemm_ws_k<<<dim3(H_ / 64, B_ / 256, 4), dim3(256), 0, stream>>>(
      visbf, VIS_, Wvisbf, VIS_, 512, parts, nullptr, H_, B_);
  reduce_norm_k<<<dim3(B_), dim3(256), 0, stream>>>(parts, 4, nullptr, 0, vbf, nullptr);

  // ---- encoder LSTM (t=0 folds h0 into biasc0)
  for (int t = 0; t < L_; ++t) {
    const ushortT* hin = (t == 0) ? nullptr : ((t & 1) ? henc1 : henc0);
    ushortT* hout = (t & 1) ? henc0 : henc1;
    lstm5_k<<<dim3(16, 32), dim3(512), 0, stream>>>(
        hin, Wfrag, xs_enc + (size_t)t * B_ * EP_,
        (t == 0) ? biasc0 : biasc, cenc, (t == 0) ? 1 : 0,
        hout, selbf, lens, t, nullptr, nullptr, nullptr, -1);
  }

  // ---- enc linear (z=1) + bias/relu/rownorm -> tencbf
  gemm_ws_k<<<dim3(H_ / 64, B_ / 256, 1), dim3(256), 0, stream>>>(
      selbf, H_, Wencbf, H_, 512, parts, nullptr, H_, B_);
  reduce_norm_k<<<dim3(B_), dim3(256), 0, stream>>>(parts, 1, b_enc, 1, tencbf, nullptr);

  // ---- attention
  gemm_ws_k<<<dim3(B_ / 64, B_ / 256, 1), dim3(256), 0, stream>>>(
      tencbf, H_, vbf, H_, 512, nullptr, Pbf, B_, B_);
  softmax_bf_rows_k<<<dim3(B_), dim3(256), 0, stream>>>(Pbf);
  transpose_bf_k<<<dim3(H_ / 32, B_ / 32), dim3(256), 0, stream>>>(vbf, Vtbf, B_, H_);
  gemm_ws_k<<<dim3(H_ / 64, B_ / 256, 4), dim3(256), 0, stream>>>(
      Pbf, B_, Vtbf, B_, 1024, parts, nullptr, H_, B_);
  reduce_norm_k<<<dim3(B_), dim3(256), 0, stream>>>(parts, 4, nullptr, 0, hdec0, cdec);

  // ---- decoder LSTM with fused previous-step NLL (t>=1), final NLL standalone
  for (int t = 0; t < L_; ++t) {
    const ushortT* hin = (t & 1) ? hdec1 : hdec0;
    ushortT* hout = (t & 1) ? hdec0 : hdec1;
    dim3 grid = (t > 0) ? dim3(20, 32) : dim3(16, 32);
    lstm5_k<<<grid, dim3(512), 0, stream>>>(
        hin, Wfrag, xs_dec + (size_t)t * B_ * EP_,
        biasc, cdec, 0, hout, nullptr, nullptr, t,
        Woutfrag, text, out, t - 1);
  }
  // h_15 lives in hdec0 (t=15 odd -> hout = hdec0)
  dec_loss3_k<<<dim3(B_ / 16), dim3(256), 0, stream>>>(hdec0, Woutfrag, text, L_ - 1, out);
}

// Round 11
// 1148.703 us; speedup vs baseline: 3.7210x; 1.0067x over previous
//
#include <hip/hip_runtime.h>
#include <math.h>

#define B_    4096
#define L_    16
#define E_    50
#define EP_   64
#define H_    512
#define G4_   2048
#define V_    128
#define VIS_  2048

typedef unsigned short ushortT;
typedef ushortT ushort8 __attribute__((ext_vector_type(8)));
typedef ushortT ushort4v __attribute__((ext_vector_type(4)));
typedef short   short8  __attribute__((ext_vector_type(8)));
typedef float   f32x4   __attribute__((ext_vector_type(4)));

__device__ __forceinline__ ushortT f2bf(float f) {
  union { float f; unsigned u; } v; v.f = f;
  unsigned u = v.u;
  u += 0x7fffu + ((u >> 16) & 1u);
  return (ushortT)(u >> 16);
}
__device__ __forceinline__ float bf2f(ushortT h) {
  union { unsigned u; float f; } v; v.u = ((unsigned)h) << 16;
  return v.f;
}
__device__ __forceinline__ float sigm(float x) { return 1.f / (1.f + __expf(-x)); }
__device__ __forceinline__ float tanh_f(float x) { return 1.f - 2.f / (__expf(2.f * x) + 1.f); }

// ================================================================ mega prep (grid 30832 x 256)
__global__ void prep_all_k(const float* __restrict__ visual, const int* __restrict__ text,
                           const float* __restrict__ emb,
                           const float* __restrict__ W_ih, const float* __restrict__ W_hh,
                           const float* __restrict__ b_ih, const float* __restrict__ b_hh,
                           const float* __restrict__ W_enc, const float* __restrict__ W_out,
                           const float* __restrict__ W_vis,
                           ushortT* __restrict__ xs_enc, ushortT* __restrict__ xs_dec,
                           ushortT* __restrict__ Wfrag, ushortT* __restrict__ Woutfrag,
                           float* __restrict__ biasc, float* __restrict__ biasc0,
                           ushortT* __restrict__ Wvisbf, ushortT* __restrict__ Wencbf,
                           ushortT* __restrict__ visbf, int* __restrict__ lens) {
  int bid = blockIdx.x, tid = threadIdx.x;
  if (bid < 16384) {
    int idx = bid * 256 + tid;
    int e = idx & 63, r = idx >> 6, b = r % B_, t = r / B_;
    ushortT ve = 0, vd = 0;
    if (e < E_) {
      int ie = text[b * L_ + t];
      int id = (t == 0) ? 0 : text[b * L_ + t - 1];
      ve = f2bf(emb[ie * E_ + e]);
      vd = f2bf(emb[id * E_ + e]);
    }
    xs_enc[idx] = ve; xs_dec[idx] = vd;
  } else if (bid < 16960) {                           // Wfrag: 32 slices x 18 ks x 4 ni x 64 ln
    int idx8 = (bid - 16384) * 256 + tid;
    int s = idx8 / 4608;
    int rem = idx8 - s * 4608;
    int ks = rem >> 8;
    int rem2 = rem & 255;
    int ni = rem2 >> 6, ln = rem2 & 63;
    int row = s * 64 + ni * 16 + (ln & 15);
    int kc = (ln >> 4) * 8;
    int j = row >> 2, qg = row & 3;
    int srow = qg * H_ + j;
    ushort8 val;
    if (ks < 16) {
      const float* src = W_hh + (size_t)srow * H_ + ks * 32 + kc;
#pragma unroll
      for (int x = 0; x < 8; ++x) val[x] = f2bf(src[x]);
    } else {
      int kb = (ks - 16) * 32 + kc;
#pragma unroll
      for (int x = 0; x < 8; ++x)
        val[x] = (kb + x < E_) ? f2bf(W_ih[(size_t)srow * E_ + kb + x]) : (ushortT)0;
    }
    *(ushort8*)(&Wfrag[(size_t)idx8 * 8]) = val;
  } else if (bid < 16992) {                           // Woutfrag
    int idx8 = (bid - 16960) * 256 + tid;
    int ks = idx8 >> 9;
    int rem = idx8 & 511;
    int nf = rem >> 6, ln = rem & 63;
    int row = nf * 16 + (ln & 15);
    int kc = ks * 32 + (ln >> 4) * 8;
    const float* src = W_out + (size_t)row * H_ + kc;
    ushort8 val;
#pragma unroll
    for (int x = 0; x < 8; ++x) val[x] = f2bf(src[x]);
    *(ushort8*)(&Woutfrag[(size_t)idx8 * 8]) = val;
  } else if (bid < 21088) {
    int idx = (bid - 16992) * 256 + tid;
    Wvisbf[idx] = f2bf(W_vis[idx]);
  } else if (bid < 22112) {
    int idx = (bid - 21088) * 256 + tid;
    Wencbf[idx] = f2bf(W_enc[idx]);
  } else if (bid < 30304) {
    int i = (bid - 22112) * 256 + tid;
    float4 v = ((const float4*)visual)[i];
    ushort4v o;
    o[0] = f2bf(v.x); o[1] = f2bf(v.y); o[2] = f2bf(v.z); o[3] = f2bf(v.w);
    ((ushort4v*)visbf)[i] = o;
  } else if (bid < 30320) {
    int b = (bid - 30304) * 256 + tid;
    int c = 0;
    for (int t = 0; t < L_; ++t) c += (text[b * L_ + t] != 0) ? 1 : 0;
    lens[b] = c;
  } else {                                            // biasc / biasc0, one wave per gate-row
    int wave = tid >> 6, lane = tid & 63;
    int p = (bid - 30320) * 4 + wave;
    int j = p >> 2, q = p & 3, o = q * H_ + j;
    const float* wr = W_hh + (size_t)o * H_;
    float rs = 0.f;
#pragma unroll
    for (int k = 0; k < H_ / 64; ++k) rs += wr[lane + k * 64];
#pragma unroll
    for (int d = 1; d < 64; d <<= 1) rs += __shfl_xor(rs, d);
    if (lane == 0) {
      float base = b_ih[o] + b_hh[o];
      biasc[p] = base;
      biasc0[p] = base + 0.1f * rs;
    }
  }
}

// ================================================================ gemm_ws2: 512 threads, 128x128 tile,
// double-buffered 4-ks (128-wide) LDS window; one A-read per 128-col block.
// Output: bf16 direct (Cb) or fp32 partial Cf + z*Mtot*ldc (disjoint per z).
__global__ __launch_bounds__(512, 2)
void gemm_ws2_k(const ushortT* __restrict__ A, int lda,
                const ushortT* __restrict__ Bp, int ldb, int kchunk,
                float* __restrict__ Cf, ushortT* __restrict__ Cb,
                int ldc, int Mtot) {
  __shared__ ushortT wl[2][16384];            // 2 x 32 KB
  const int tid = threadIdx.x;
  const int n0 = blockIdx.x * 128;
  const int m0 = blockIdx.y * 128;
  const int lane = tid & 63, wave = tid >> 6;
  const int q = lane >> 4, r = lane & 15;
  const int ak = q * 8;
  const int wrow = m0 + wave * 16;
  const int kbeg = blockIdx.z * kchunk;
  const int nchunks = kchunk >> 7;

  auto stage = [&](int kb, int buf) {
#pragma unroll
    for (int i = 0; i < 4; ++i) {
      int u = tid + i * 512;                  // 0..2047
      int f = u >> 6, l = u & 63;
      int kk = f >> 3, nn = f & 7;
      int row = n0 + nn * 16 + (l & 15);
      int kc = kb + kk * 32 + (l >> 4) * 8;
      *(ushort8*)(&wl[buf][((kk * 8 + nn) * 64 + l) * 8]) =
          *(const ushort8*)(&Bp[(size_t)row * ldb + kc]);
    }
  };

  f32x4 acc[8];
#pragma unroll
  for (int nn = 0; nn < 8; ++nn)
#pragma unroll
    for (int x = 0; x < 4; ++x) acc[nn][x] = 0.f;

  stage(kbeg, 0);
  __syncthreads();
  for (int ch = 0; ch < nchunks; ++ch) {
    int buf = ch & 1;
    if (ch + 1 < nchunks) stage(kbeg + (ch + 1) * 128, buf ^ 1);
    int kb = kbeg + ch * 128;
#pragma unroll
    for (int kk = 0; kk < 4; ++kk) {
      short8 a = *(const short8*)(&A[(size_t)(wrow + r) * lda + kb + kk * 32 + ak]);
#pragma unroll
      for (int nn = 0; nn < 8; ++nn) {
        short8 b = *(const short8*)(&wl[buf][((kk * 8 + nn) * 64 + lane) * 8]);
        acc[nn] = __builtin_amdgcn_mfma_f32_16x16x32_bf16(a, b, acc[nn], 0, 0, 0);
      }
    }
    __syncthreads();
  }

  if (Cb) {
#pragma unroll
    for (int nn = 0; nn < 8; ++nn) {
      int col = n0 + nn * 16 + r;
#pragma unroll
      for (int rr = 0; rr < 4; ++rr)
        Cb[(size_t)(wrow + q * 4 + rr) * ldc + col] = f2bf(acc[nn][rr]);
    }
  } else {
    float* Cz = Cf + (size_t)blockIdx.z * Mtot * ldc;
#pragma unroll
    for (int nn = 0; nn < 8; ++nn) {
      int col = n0 + nn * 16 + r;
#pragma unroll
      for (int rr = 0; rr < 4; ++rr)
        Cz[(size_t)(wrow + q * 4 + rr) * ldc + col] = acc[nn][rr];
    }
  }
}

// ================================================================ reduce partials + bias/relu + rownorm
// outb: bf16 normalized; outc: optional bf16 copy (decoder c0)
__global__ void reduce_norm_k(const float* __restrict__ parts, int nparts,
                              const float* __restrict__ bias, int relu,
                              ushortT* __restrict__ outb, ushortT* __restrict__ outc) {
  int b = blockIdx.x, tid = threadIdx.x;
  float v[2];
  float ss = 0.f;
#pragma unroll
  for (int l = 0; l < 2; ++l) {
    int i = tid + l * 256;
    float s = 0.f;
    for (int p = 0; p < nparts; ++p)
      s += parts[(size_t)p * B_ * H_ + (size_t)b * H_ + i];
    if (bias) s += bias[i];
    if (relu) s = fmaxf(s, 0.f);
    v[l] = s;
    ss += s * s;
  }
  __shared__ float red[256];
  red[tid] = ss; __syncthreads();
  for (int st = 128; st > 0; st >>= 1) { if (tid < st) red[tid] += red[tid + st]; __syncthreads(); }
  float inv = 1.f / sqrtf(red[0]);
#pragma unroll
  for (int l = 0; l < 2; ++l) {
    int i = tid + l * 256;
    float x = v[l] * inv;
    ushortT xb = f2bf(x);
    outb[(size_t)b * H_ + i] = xb;
    if (outc) outc[(size_t)b * H_ + i] = xb;
  }
}

// ================================================================ lstm5 (bf16 c state)
__global__ __launch_bounds__(512, 2)
void lstm5_k(const ushortT* __restrict__ hin, const ushortT* __restrict__ Wfrag,
             const ushortT* __restrict__ xs, const float* __restrict__ biasc,
             ushortT* __restrict__ c, int cconst,
             ushortT* __restrict__ hout, ushortT* __restrict__ sel,
             const int* __restrict__ lens, int t,
             const ushortT* __restrict__ Woutfrag, const int* __restrict__ text,
             float* __restrict__ out, int losst) {
  __shared__ char smem[67584];
  const int tid = threadIdx.x;
  const int lane = tid & 63, wave = tid >> 6;
  const int q = lane >> 4, r = lane & 15;
  const int ak = q * 8;

  if (blockIdx.x >= 16) {
    // fused NLL for previous step's h (= hin); two 4-wave groups x 16 rows
    float* pbuf = (float*)smem;
    const int group = wave >> 2, wv = wave & 3;
    float* pbase = pbuf + group * 8448;
    const int row0g = blockIdx.y * 128 + (blockIdx.x - 16) * 32 + group * 16;
    f32x4 dacc[8];
#pragma unroll
    for (int i = 0; i < 8; ++i)
#pragma unroll
      for (int x = 0; x < 4; ++x) dacc[i][x] = 0.f;
#pragma unroll
    for (int ks = 0; ks < 4; ++ks) {
      int ksg = wv * 4 + ks;
      short8 a = *(const short8*)(&hin[(size_t)(row0g + r) * H_ + ksg * 32 + ak]);
#pragma unroll
      for (int nf = 0; nf < 8; ++nf) {
        short8 b = *(const short8*)(&Woutfrag[((ksg * 8 + nf) * 64 + lane) * 8]);
        dacc[nf] = __builtin_amdgcn_mfma_f32_16x16x32_bf16(a, b, dacc[nf], 0, 0, 0);
      }
    }
#pragma unroll
    for (int nf = 0; nf < 8; ++nf)
#pragma unroll
      for (int rr = 0; rr < 4; ++rr)
        pbase[(wv * 16 + q * 4 + rr) * 132 + nf * 16 + r] = dacc[nf][rr];
    __syncthreads();
    int g = tid & 255;
    int grp2 = tid >> 8;
    float* pb2 = pbuf + grp2 * 8448;
    int row = g >> 4, lp = g & 15;
    f32x4 s0, s1;
#pragma unroll
    for (int rr = 0; rr < 4; ++rr) { s0[rr] = 0.f; s1[rr] = 0.f; }
#pragma unroll
    for (int wv2 = 0; wv2 < 4; ++wv2) {
      s0 += *(const f32x4*)(&pb2[(wv2 * 16 + row) * 132 + lp * 8]);
      s1 += *(const f32x4*)(&pb2[(wv2 * 16 + row) * 132 + lp * 8 + 4]);
    }
    float mx = s0[0];
#pragma unroll
    for (int rr = 1; rr < 4; ++rr) mx = fmaxf(mx, s0[rr]);
#pragma unroll
    for (int rr = 0; rr < 4; ++rr) mx = fmaxf(mx, s1[rr]);
#pragma unroll
    for (int d = 1; d < 16; d <<= 1) mx = fmaxf(mx, __shfl_xor(mx, d));
    float sum = 0.f;
#pragma unroll
    for (int rr = 0; rr < 4; ++rr) sum += __expf(s0[rr] - mx) + __expf(s1[rr] - mx);
#pragma unroll
    for (int d = 1; d < 16; d <<= 1) sum += __shfl_xor(sum, d);
    float lse = mx + __logf(sum);
    int b = blockIdx.y * 128 + (blockIdx.x - 16) * 32 + grp2 * 16 + row;
    int tgt = text[b * L_ + losst];
    if ((tgt >> 3) == lp) {
      float lv = (tgt & 4) ? s1[tgt & 3] : s0[tgt & 3];
      float loss = (lse - lv) * (1.f / (float)L_);
      if (losst == 0) out[b] = loss;
      else out[b] += loss;
    }
    return;
  }

  // LSTM gate GEMM + cell update
  ushortT* wl = (ushortT*)smem;
  const int s2 = blockIdx.x;
  const int m0 = blockIdx.y * 128;
  const int wrow = m0 + wave * 16;
  const ushortT* Wbase = Wfrag + (size_t)(2 * s2) * 36864;

  auto stage = [&](int chunk, int buf) {
#pragma unroll
    for (int i = 0; i < 3; ++i) {
      int u = tid + i * 512;
      int f = u >> 6, l = u & 63;
      int kk = f >> 3, nn = f & 7;
      int ks = chunk * 3 + kk;
      const ushortT* src = Wbase + (size_t)(nn >> 2) * 36864 + ((size_t)(ks * 4 + (nn & 3)) * 64 + l) * 8;
      *(ushort8*)(&wl[(size_t)buf * 12288 + ((kk * 8 + nn) * 64 + l) * 8]) = *(const ushort8*)src;
    }
  };

  f32x4 acc[8];
#pragma unroll
  for (int nn = 0; nn < 8; ++nn)
#pragma unroll
    for (int x = 0; x < 4; ++x) acc[nn][x] = 0.f;

  const int cstart = hin ? 0 : 5;
  stage(cstart, 0);
  __syncthreads();
  for (int ch = cstart; ch < 6; ++ch) {
    int buf = (ch - cstart) & 1;
    if (ch < 5) stage(ch + 1, buf ^ 1);
#pragma unroll
    for (int kk = 0; kk < 3; ++kk) {
      int ks = ch * 3 + kk;
      if (!hin && ks < 16) continue;
      short8 a;
      if (ks < 16) a = *(const short8*)(&hin[(size_t)(wrow + r) * H_ + ks * 32 + ak]);
      else         a = *(const short8*)(&xs[(size_t)(wrow + r) * EP_ + (ks - 16) * 32 + ak]);
#pragma unroll
      for (int nn = 0; nn < 8; ++nn) {
        short8 b = *(const short8*)(&wl[(size_t)buf * 12288 + ((kk * 8 + nn) * 64 + lane) * 8]);
        acc[nn] = __builtin_amdgcn_mfma_f32_16x16x32_bf16(a, b, acc[nn], 0, 0, 0);
      }
    }
    __syncthreads();
  }

  // epilogue: shuffle-transpose + cell update; 16 rows x 128 cols per wave
#pragma unroll
  for (int nn = 0; nn < 8; ++nn) {
    int row = wrow + q * 4 + (r & 3);
    float v0 = acc[nn][0], v1 = acc[nn][1], v2 = acc[nn][2], v3 = acc[nn][3];
    float s0 = __shfl_xor(v0, 2), s1 = __shfl_xor(v1, 2),
          s2s = __shfl_xor(v2, 2), s3 = __shfl_xor(v3, 2);
    float a0, a1, a2, a3;
    if (r & 2) { a0 = s2s; a1 = s3; a2 = v2; a3 = v3; }
    else       { a0 = v0; a1 = v1; a2 = s0; a3 = s1; }
    float t0 = __shfl_xor(a0, 1), t1 = __shfl_xor(a1, 1),
          t2 = __shfl_xor(a2, 1), t3 = __shfl_xor(a3, 1);
    float g0, g1, g2, g3;
    if (r & 1) { g0 = t1; g1 = a1; g2 = t3; g3 = a3; }
    else       { g0 = a0; g1 = t0; g2 = a2; g3 = t2; }
    int j = s2 * 32 + nn * 4 + (r >> 2);
    f32x4 bb = *(const f32x4*)(&biasc[j * 4]);
    float si = sigm(g0 + bb[0]);
    float sf = sigm(g1 + bb[1]);
    float tg = tanh_f(g2 + bb[2]);
    float so = sigm(g3 + bb[3]);
    size_t ci = (size_t)row * H_ + j;
    float cprev = cconst ? 0.1f : bf2f(c[ci]);
    float cn = sf * cprev + si * tg;
    float hn = so * tanh_f(cn);
    c[ci] = f2bf(cn);
    ushortT hb16 = f2bf(hn);
    hout[ci] = hb16;
    if (sel) {
      int len = lens[row];
      int eff = (len == 0) ? L_ : len;
      if (t == eff - 1) sel[ci] = hb16;
    }
  }
}

// ================================================================ standalone decoder loss (final step)
__global__ __launch_bounds__(256)
void dec_loss3_k(const ushortT* __restrict__ h, const ushortT* __restrict__ Woutfrag,
                 const int* __restrict__ text, int t, float* __restrict__ out) {
  __shared__ float pbuf[4 * 16 * 132];
  const int tid = threadIdx.x;
  const int row0 = blockIdx.x * 16;
  const int lane = tid & 63, wave = tid >> 6;
  const int am = lane & 15, ak = (lane >> 4) * 8;

  f32x4 acc[8];
#pragma unroll
  for (int i = 0; i < 8; ++i)
#pragma unroll
    for (int r = 0; r < 4; ++r) acc[i][r] = 0.f;

#pragma unroll
  for (int ks = 0; ks < 4; ++ks) {
    int ksg = wave * 4 + ks;
    short8 a = *(const short8*)(&h[(size_t)(row0 + am) * H_ + ksg * 32 + ak]);
#pragma unroll
    for (int nf = 0; nf < 8; ++nf) {
      short8 b = *(const short8*)(&Woutfrag[((ksg * 8 + nf) * 64 + lane) * 8]);
      acc[nf] = __builtin_amdgcn_mfma_f32_16x16x32_bf16(a, b, acc[nf], 0, 0, 0);
    }
  }
#pragma unroll
  for (int nf = 0; nf < 8; ++nf)
#pragma unroll
    for (int r = 0; r < 4; ++r) {
      int rowL = (lane >> 4) * 4 + r;
      pbuf[(wave * 16 + rowL) * 132 + nf * 16 + am] = acc[nf][r];
    }
  __syncthreads();

  int row = tid >> 4, lp = tid & 15;
  f32x4 s0, s1;
#pragma unroll
  for (int r = 0; r < 4; ++r) { s0[r] = 0.f; s1[r] = 0.f; }
#pragma unroll
  for (int wv = 0; wv < 4; ++wv) {
    s0 += *(const f32x4*)(&pbuf[(wv * 16 + row) * 132 + lp * 8]);
    s1 += *(const f32x4*)(&pbuf[(wv * 16 + row) * 132 + lp * 8 + 4]);
  }
  float mx = s0[0];
#pragma unroll
  for (int r = 1; r < 4; ++r) mx = fmaxf(mx, s0[r]);
#pragma unroll
  for (int r = 0; r < 4; ++r) mx = fmaxf(mx, s1[r]);
#pragma unroll
  for (int d = 1; d < 16; d <<= 1) mx = fmaxf(mx, __shfl_xor(mx, d));
  float sum = 0.f;
#pragma unroll
  for (int r = 0; r < 4; ++r) sum += __expf(s0[r] - mx) + __expf(s1[r] - mx);
#pragma unroll
  for (int d = 1; d < 16; d <<= 1) sum += __shfl_xor(sum, d);
  float lse = mx + __logf(sum);
  int b = row0 + row;
  int tgt = text[b * L_ + t];
  if ((tgt >> 3) == lp) {
    float lv = (tgt & 4) ? s1[tgt & 3] : s0[tgt & 3];
    float loss = (lse - lv) * (1.f / (float)L_);
    if (t == 0) out[b] = loss;
    else out[b] += loss;
  }
}

// ================================================================ softmax / transpose
__global__ __launch_bounds__(256)
void softmax_bf_rows_k(ushortT* __restrict__ P) {
  int rr = blockIdx.x, tid = threadIdx.x;
  ushortT* row = P + (size_t)rr * B_;
  float xv[16];
  float m = -1e30f;
#pragma unroll
  for (int l = 0; l < 16; ++l) { float v = bf2f(row[tid + l * 256]); xv[l] = v; m = fmaxf(m, v); }
  __shared__ float red[256];
  red[tid] = m; __syncthreads();
  for (int st = 128; st > 0; st >>= 1) { if (tid < st) red[tid] = fmaxf(red[tid], red[tid + st]); __syncthreads(); }
  m = red[0]; __syncthreads();
  float s = 0.f;
#pragma unroll
  for (int l = 0; l < 16; ++l) { float e = __expf(xv[l] - m); xv[l] = e; s += e; }
  red[tid] = s; __syncthreads();
  for (int st = 128; st > 0; st >>= 1) { if (tid < st) red[tid] += red[tid + st]; __syncthreads(); }
  float inv = 1.f / red[0];
#pragma unroll
  for (int l = 0; l < 16; ++l) row[tid + l * 256] = f2bf(xv[l] * inv);
}

__global__ void transpose_bf_k(const ushortT* __restrict__ in, ushortT* __restrict__ out,
                               int R, int Ccols) {
  __shared__ ushortT tile[32][33];
  int c0 = blockIdx.x * 32, r0 = blockIdx.y * 32;
  int tx = threadIdx.x & 31, ty = threadIdx.x >> 5;
  for (int i = ty; i < 32; i += 8) tile[i][tx] = in[(size_t)(r0 + i) * Ccols + c0 + tx];
  __syncthreads();
  for (int i = ty; i < 32; i += 8) out[(size_t)(c0 + i) * R + r0 + tx] = tile[tx][i];
}

// ================================================================ launch
extern "C" void kernel_launch(void* const* d_in, const int* in_sizes, int n_in,
                              void* d_out, int out_size, void* d_ws, size_t ws_size,
                              hipStream_t stream) {
  const float* visual = (const float*)d_in[0];
  const int*   text   = (const int*)  d_in[1];
  const float* emb    = (const float*)d_in[2];
  const float* W_ih   = (const float*)d_in[3];
  const float* W_hh   = (const float*)d_in[4];
  const float* b_ih   = (const float*)d_in[5];
  const float* b_hh   = (const float*)d_in[6];
  const float* W_enc  = (const float*)d_in[7];
  const float* b_enc  = (const float*)d_in[8];
  const float* W_out  = (const float*)d_in[9];
  const float* W_vis  = (const float*)d_in[10];
  float* out = (float*)d_out;

  char* w = (char*)d_ws;
  auto alloc = [&](size_t bytes) { char* p = w; w += (bytes + 255) & ~(size_t)255; return p; };
  ushortT* xs_enc   = (ushortT*)alloc((size_t)L_ * B_ * EP_ * 2);
  ushortT* xs_dec   = (ushortT*)alloc((size_t)L_ * B_ * EP_ * 2);
  ushortT* Wfrag    = (ushortT*)alloc((size_t)32 * 18 * 4 * 64 * 8 * 2);
  ushortT* Woutfrag = (ushortT*)alloc((size_t)16 * 8 * 64 * 8 * 2);
  float*   biasc    = (float*)  alloc((size_t)G4_ * 4);
  float*   biasc0   = (float*)  alloc((size_t)G4_ * 4);
  ushortT* Wvisbf   = (ushortT*)alloc((size_t)H_ * VIS_ * 2);
  ushortT* Wencbf   = (ushortT*)alloc((size_t)H_ * H_ * 2);
  ushortT* visbf    = (ushortT*)alloc((size_t)B_ * VIS_ * 2);
  ushortT* henc0    = (ushortT*)alloc((size_t)B_ * H_ * 2);
  ushortT* henc1    = (ushortT*)alloc((size_t)B_ * H_ * 2);
  ushortT* cenc     = (ushortT*)alloc((size_t)B_ * H_ * 2);
  ushortT* selbf    = (ushortT*)alloc((size_t)B_ * H_ * 2);
  ushortT* vbf      = (ushortT*)alloc((size_t)B_ * H_ * 2);
  ushortT* tencbf   = (ushortT*)alloc((size_t)B_ * H_ * 2);
  ushortT* Pbf      = (ushortT*)alloc((size_t)B_ * B_ * 2);
  ushortT* Vtbf     = (ushortT*)alloc((size_t)H_ * B_ * 2);
  ushortT* cdec     = (ushortT*)alloc((size_t)B_ * H_ * 2);
  ushortT* hdec0    = (ushortT*)alloc((size_t)B_ * H_ * 2);
  ushortT* hdec1    = (ushortT*)alloc((size_t)B_ * H_ * 2);
  int*     lens     = (int*)    alloc((size_t)B_ * 4);
  float*   parts    = (float*)  alloc((size_t)4 * B_ * H_ * 4);

  // ---- mega prep
  prep_all_k<<<dim3(30832), dim3(256), 0, stream>>>(
      visual, text, emb, W_ih, W_hh, b_ih, b_hh, W_enc, W_out, W_vis,
      xs_enc, xs_dec, Wfrag, Woutfrag, biasc, biasc0,
      Wvisbf, Wencbf, visbf, lens);

  // ---- visual projection (z=2, kchunk=1024) + rownorm -> vbf
  gemm_ws2_k<<<dim3(H_ / 128, B_ / 128, 2), dim3(512), 0, stream>>>(
      visbf, VIS_, Wvisbf, VIS_, 1024, parts, nullptr, H_, B_);
  reduce_norm_k<<<dim3(B_), dim3(256), 0, stream>>>(parts, 2, nullptr, 0, vbf, nullptr);

  // ---- encoder LSTM (t=0 folds h0 into biasc0)
  for (int t = 0; t < L_; ++t) {
    const ushortT* hin = (t == 0) ? nullptr : ((t & 1) ? henc1 : henc0);
    ushortT* hout = (t & 1) ? henc0 : henc1;
    lstm5_k<<<dim3(16, 32), dim3(512), 0, stream>>>(
        hin, Wfrag, xs_enc + (size_t)t * B_ * EP_,
        (t == 0) ? biasc0 : biasc, cenc, (t == 0) ? 1 : 0,
        hout, selbf, lens, t, nullptr, nullptr, nullptr, -1);
  }

  // ---- enc linear (z=2, kchunk=256) + bias/relu/rownorm -> tencbf
  gemm_ws2_k<<<dim3(H_ / 128, B_ / 128, 2), dim3(512), 0, stream>>>(
      selbf, H_, Wencbf, H_, 256, parts, nullptr, H_, B_);
  reduce_norm_k<<<dim3(B_), dim3(256), 0, stream>>>(parts, 2, b_enc, 1, tencbf, nullptr);

  // ---- attention
  gemm_ws2_k<<<dim3(B_ / 128, B_ / 128, 1), dim3(512), 0, stream>>>(
      tencbf, H_, vbf, H_, 512, nullptr, Pbf, B_, B_);
  softmax_bf_rows_k<<<dim3(B_), dim3(256), 0, stream>>>(Pbf);
  transpose_bf_k<<<dim3(H_ / 32, B_ / 32), dim3(256), 0, stream>>>(vbf, Vtbf, B_, H_);
  gemm_ws2_k<<<dim3(H_ / 128, B_ / 128, 4), dim3(512), 0, stream>>>(
      Pbf, B_, Vtbf, B_, 1024, parts, nullptr, H_, B_);
  reduce_norm_k<<<dim3(B_), dim3(256), 0, stream>>>(parts, 4, nullptr, 0, hdec0, cdec);

  // ---- decoder LSTM with fused previous-step NLL (t>=1), final NLL standalone
  for (int t = 0; t < L_; ++t) {
    const ushortT* hin = (t & 1) ? hdec1 : hdec0;
    ushortT* hout = (t & 1) ? hdec0 : hdec1;
    dim3 grid = (t > 0) ? dim3(20, 32) : dim3(16, 32);
    lstm5_k<<<grid, dim3(512), 0, stream>>>(
        hin, Wfrag, xs_dec + (size_t)t * B_ * EP_,
        biasc, cdec, 0, hout, nullptr, nullptr, t,
        Woutfrag, text, out, t - 1);
  }
  // h_15 lives in hdec0 (t=15 odd -> hout = hdec0)
  dec_loss3_k<<<dim3(B_ / 16), dim3(256), 0, stream>>>(hdec0, Woutfrag, text, L_ - 1, out);
}